// Round 12
// baseline (195.071 us; speedup 1.0000x reference)
//
#include <hip/hip_runtime.h>
#include <hip/hip_cooperative_groups.h>

namespace cg = cooperative_groups;

#define N 4096
#define D 1024
#define EPSF 1e-6f

typedef _Float16 f16;
typedef f16 f16x8 __attribute__((ext_vector_type(8)));
typedef float f32x4 __attribute__((ext_vector_type(4)));
typedef unsigned long long u64;

#define PLANE ((size_t)2048 * 1024)  // f16 elements per packed plane

struct WS {
  int n_A, mid, n2, n_B, n_resid, pad[3];
  float a[N];
  float diag[N];
  int A1idx[N];
  int A2idx[N];
  int Bidx[N];
  int matches[N];
  int residIdx[N];
  u64 bestKey[2048];
};

struct MaskSh {   // carved from the gemm LDS buffer (phases don't overlap)
  double dred[4], dred2[4];
  float bcast[2];
  int hist[256];
  int wsum[4];
  unsigned sPrefix;
  int sRank;
};

__device__ __forceinline__ u64 packKey(float v, int j) {
  unsigned u = __float_as_uint(v);
  unsigned m = (u & 0x80000000u) ? ~u : (u | 0x80000000u);
  return ((u64)m << 32) | (unsigned)(~(unsigned)j);
}

__global__ void __launch_bounds__(256) k_all(const float* __restrict__ x,
                                             const float* __restrict__ attn,
                                             f16* __restrict__ PAhi, f16* __restrict__ PAlo,
                                             f16* __restrict__ PBhi, f16* __restrict__ PBlo,
                                             float* __restrict__ out, WS* __restrict__ ws) {
  cg::grid_group grid = cg::this_grid();
  __shared__ __align__(16) f16 lds[2][4][64 * 64];  // 64 KiB, aliased by mask/match

  const int tid = threadIdx.x;
  const int lane = tid & 63;
  const int wv = tid >> 6;
  const int bid = blockIdx.x;

  // ================= P1: prep — row means of x + attn diagonal =================
  {
    #pragma unroll
    for (int rr = 0; rr < 4; rr++) {
      int row = bid * 16 + wv * 4 + rr;
      const float4* xr = (const float4*)(x + (size_t)row * D);
      float sm = 0.f;
      #pragma unroll
      for (int it = 0; it < 4; it++) {
        float4 v = xr[it * 64 + lane];
        sm += v.x + v.y + v.z + v.w;
      }
      for (int o = 32; o; o >>= 1) sm += __shfl_down(sm, o, 64);
      if (lane == 0) {
        ws->a[row] = sm * (1.0f / D);
        ws->diag[row] = attn[(size_t)row * (N + 1)];
      }
    }
  }
  grid.sync();

  // ================= P2: mask (block 0 only; round-11 verified body) =================
  if (bid == 0) {
    MaskSh& sh = *(MaskSh*)lds;

    #pragma unroll
    for (int q = 0; q < 8; q++) ws->bestKey[tid * 8 + q] = 0ull;

    // stats of a
    float av[16];
    double s = 0.0, s2 = 0.0;
    #pragma unroll
    for (int q = 0; q < 4; q++) {
      float4 va = ((const float4*)ws->a)[tid * 4 + q];
      float f4[4] = {va.x, va.y, va.z, va.w};
      #pragma unroll
      for (int e = 0; e < 4; e++) {
        av[q * 4 + e] = f4[e];
        s += f4[e]; s2 += (double)f4[e] * f4[e];
      }
    }
    for (int o = 32; o; o >>= 1) { s += __shfl_down(s, o, 64); s2 += __shfl_down(s2, o, 64); }
    if (lane == 0) { sh.dred[wv] = s; sh.dred2[wv] = s2; }
    __syncthreads();
    if (tid == 0) {
      double t1 = sh.dred[0] + sh.dred[1] + sh.dred[2] + sh.dred[3];
      double t2 = sh.dred2[0] + sh.dred2[1] + sh.dred2[2] + sh.dred2[3];
      sh.bcast[0] = (float)(t1 / N);
      sh.bcast[1] = (float)sqrt((t2 - t1 * t1 / N) / (N - 1));
    }
    __syncthreads();
    float meanA = sh.bcast[0], stdA = sh.bcast[1];

    // Il = z^2 * diag + its stats
    float il[16];
    s = 0.0; s2 = 0.0;
    #pragma unroll
    for (int q = 0; q < 4; q++) {
      float4 dg = ((const float4*)ws->diag)[tid * 4 + q];
      float d4[4] = {dg.x, dg.y, dg.z, dg.w};
      #pragma unroll
      for (int e = 0; e < 4; e++) {
        float z = (av[q * 4 + e] - meanA) / (stdA + EPSF);
        float I = z * z * d4[e];
        il[q * 4 + e] = I;
        s += I; s2 += (double)I * I;
      }
    }
    for (int o = 32; o; o >>= 1) { s += __shfl_down(s, o, 64); s2 += __shfl_down(s2, o, 64); }
    __syncthreads();
    if (lane == 0) { sh.dred[wv] = s; sh.dred2[wv] = s2; }
    __syncthreads();
    if (tid == 0) {
      double t1 = sh.dred[0] + sh.dred[1] + sh.dred[2] + sh.dred[3];
      double t2 = sh.dred2[0] + sh.dred2[1] + sh.dred2[2] + sh.dred2[3];
      sh.bcast[0] = (float)(t1 / N);
      sh.bcast[1] = (float)sqrt((t2 - t1 * t1 / N) / (N - 1));
      sh.sPrefix = 0u; sh.sRank = (N - 1) / 2;
    }
    __syncthreads();
    float meanI = sh.bcast[0], stdI = sh.bcast[1];

    float sv[16]; unsigned ab[16];
    #pragma unroll
    for (int q = 0; q < 16; q++) {
      float sval = (il[q] - meanI) / (stdI + EPSF);
      sv[q] = sval;
      ab[q] = __float_as_uint(fabsf(sval));
    }

    // radix select rank-2047 of |s| bit patterns
    for (int p = 3; p >= 0; p--) {
      sh.hist[tid] = 0;
      __syncthreads();
      unsigned pre = sh.sPrefix;
      int rk = sh.sRank;
      int shf = p * 8;
      unsigned mHi = (p == 3) ? 0u : (0xFFFFFFFFu << (shf + 8));
      #pragma unroll
      for (int q = 0; q < 16; q++)
        if ((ab[q] & mHi) == pre) atomicAdd(&sh.hist[(ab[q] >> shf) & 255], 1);
      __syncthreads();
      int v2 = sh.hist[tid];
      int inc = v2;
      #pragma unroll
      for (int o = 1; o < 64; o <<= 1) { int u = __shfl_up(inc, o, 64); if (lane >= o) inc += u; }
      if (lane == 63) sh.wsum[wv] = inc;
      __syncthreads();
      if (tid == 0) { sh.wsum[1] += sh.wsum[0]; sh.wsum[2] += sh.wsum[1]; sh.wsum[3] += sh.wsum[2]; }
      __syncthreads();
      int incl = (wv ? sh.wsum[wv - 1] : 0) + inc;
      int E = incl - v2;
      if (v2 && rk >= E && rk < E + v2) {
        sh.sPrefix = pre | ((unsigned)tid << shf);
        sh.sRank = rk - E;
      }
      __syncthreads();
    }
    float med = __uint_as_float(sh.sPrefix);

    // mask (strict |s| > med) + stable compaction
    int msk[16], loc[16]; int tot = 0;
    #pragma unroll
    for (int q = 0; q < 16; q++) {
      bool m = fabsf(sv[q]) > med;
      msk[q] = m; loc[q] = tot; tot += (int)m;
    }
    int inc = tot;
    #pragma unroll
    for (int o = 1; o < 64; o <<= 1) { int u = __shfl_up(inc, o, 64); if (lane >= o) inc += u; }
    if (lane == 63) sh.wsum[wv] = inc;
    __syncthreads();
    if (tid == 0) { sh.wsum[1] += sh.wsum[0]; sh.wsum[2] += sh.wsum[1]; sh.wsum[3] += sh.wsum[2]; }
    __syncthreads();
    int nA = sh.wsum[3];
    int base = (wv ? sh.wsum[wv - 1] : 0) + inc - tot;
    int midl = nA >> 1;
    #pragma unroll
    for (int q = 0; q < 16; q++) {
      int i = tid * 16 + q;
      int r = base + loc[q];
      if (msk[q]) {
        if (r < midl) ws->A1idx[r] = i; else ws->A2idx[r - midl] = i;
      } else {
        ws->Bidx[i - r] = i;
      }
    }
    if (tid == 0) { ws->n_A = nA; ws->mid = midl; ws->n2 = nA - midl; ws->n_B = N - nA; }
  }
  grid.sync();

  const int mid = ws->mid, n2 = ws->n2;

  // ================= P3: pack — gather rows into tiled swizzled planes =================
  {
    int sub = tid >> 7;        // two rows per block per iteration
    int tt = tid & 127;
    #pragma unroll 1
    for (int it = 0; it < 8; it++) {
      int slot = it * 512 + bid * 2 + sub;
      const float* src = nullptr;
      f16 *dh, *dl;
      int j;
      bool valid;
      if (slot < 2048) {
        j = slot; valid = (j < mid);
        if (valid) src = x + (size_t)ws->A1idx[j] * D;
        dh = PAhi; dl = PAlo;
      } else {
        j = slot - 2048; valid = (j < n2);
        if (valid) src = x + (size_t)ws->A2idx[j] * D;
        dh = PBhi; dl = PBlo;
      }
      if (valid) {
        float4 v0 = ((const float4*)src)[tt * 2];
        float4 v1 = ((const float4*)src)[tt * 2 + 1];
        float vv[8] = {v0.x, v0.y, v0.z, v0.w, v1.x, v1.y, v1.z, v1.w};
        f16x8 h, l;
        #pragma unroll
        for (int q = 0; q < 8; q++) {
          f16 hq = (f16)vv[q];
          h[q] = hq;
          l[q] = (f16)(vv[q] - (float)hq);
        }
        int rt = j >> 6, rl = j & 63;
        int kt = tt >> 3, gl = tt & 7;
        size_t off = ((size_t)(rt * 16 + kt) << 12) + rl * 64 + ((gl ^ (rl & 7)) * 8);
        *(f16x8*)(dh + off) = h;
        *(f16x8*)(dl + off) = l;
      }
    }
  }
  grid.sync();

  // ================= P4: gemm — f16x3 MFMA + per-row argmax (round-7 body) =================
  {
    int local = bid >> 3;
    int bj = ((bid & 7) << 1) | (local >> 4);
    int bi = local & 15;
    if (bi * 64 < mid && bj * 64 < n2) {
      const int wid = wv;
      const int wr = wid >> 1, wc = wid & 1;
      const f16* plane = (wid == 0) ? PAhi : (wid == 1) ? PAlo : (wid == 2) ? PBhi : PBlo;
      const int ptile = (wid < 2) ? bi : bj;

      f16x8 pr[8];
      auto LOAD = [&](int t) {
        const f16* tb = plane + ((size_t)((ptile << 4) + t) << 12);
        #pragma unroll
        for (int i = 0; i < 8; i++) pr[i] = *(const f16x8*)(tb + i * 512 + lane * 8);
      };
      auto STORE = [&](int buf) {
        #pragma unroll
        for (int i = 0; i < 8; i++) *(f16x8*)&lds[buf][wid][i * 512 + lane * 8] = pr[i];
      };

      const int colg = lane & 15, rowg = lane >> 4;
      const int ma0 = wr * 32 + colg, ma1 = ma0 + 16;
      const int mb0 = wc * 32 + colg, mb1 = mb0 + 16;

      f32x4 zero = {0.f, 0.f, 0.f, 0.f};
      f32x4 acc[2][2];
      acc[0][0] = zero; acc[0][1] = zero; acc[1][0] = zero; acc[1][1] = zero;

#define FRAG(buf, t4, row, g) \
  (*(const f16x8*)&lds[buf][t4][(row) * 64 + ((((g) ^ ((row) & 7))) * 8)])

      LOAD(0);
      STORE(0);
      __syncthreads();
      #pragma unroll 1
      for (int t16 = 0; t16 < 16; t16++) {
        int buf = t16 & 1;
        if (t16 < 15) LOAD(t16 + 1);
        #pragma unroll
        for (int ks = 0; ks < 2; ks++) {
          int gk = ks * 4 + rowg;
          f16x8 ah0 = FRAG(buf, 0, ma0, gk), ah1 = FRAG(buf, 0, ma1, gk);
          f16x8 al0 = FRAG(buf, 1, ma0, gk), al1 = FRAG(buf, 1, ma1, gk);
          f16x8 bh0 = FRAG(buf, 2, mb0, gk), bh1 = FRAG(buf, 2, mb1, gk);
          f16x8 bl0 = FRAG(buf, 3, mb0, gk), bl1 = FRAG(buf, 3, mb1, gk);
          acc[0][0] = __builtin_amdgcn_mfma_f32_16x16x32_f16(ah0, bh0, acc[0][0], 0, 0, 0);
          acc[0][0] = __builtin_amdgcn_mfma_f32_16x16x32_f16(ah0, bl0, acc[0][0], 0, 0, 0);
          acc[0][0] = __builtin_amdgcn_mfma_f32_16x16x32_f16(al0, bh0, acc[0][0], 0, 0, 0);
          acc[0][1] = __builtin_amdgcn_mfma_f32_16x16x32_f16(ah0, bh1, acc[0][1], 0, 0, 0);
          acc[0][1] = __builtin_amdgcn_mfma_f32_16x16x32_f16(ah0, bl1, acc[0][1], 0, 0, 0);
          acc[0][1] = __builtin_amdgcn_mfma_f32_16x16x32_f16(al0, bh1, acc[0][1], 0, 0, 0);
          acc[1][0] = __builtin_amdgcn_mfma_f32_16x16x32_f16(ah1, bh0, acc[1][0], 0, 0, 0);
          acc[1][0] = __builtin_amdgcn_mfma_f32_16x16x32_f16(ah1, bl0, acc[1][0], 0, 0, 0);
          acc[1][0] = __builtin_amdgcn_mfma_f32_16x16x32_f16(al1, bh0, acc[1][0], 0, 0, 0);
          acc[1][1] = __builtin_amdgcn_mfma_f32_16x16x32_f16(ah1, bh1, acc[1][1], 0, 0, 0);
          acc[1][1] = __builtin_amdgcn_mfma_f32_16x16x32_f16(ah1, bl1, acc[1][1], 0, 0, 0);
          acc[1][1] = __builtin_amdgcn_mfma_f32_16x16x32_f16(al1, bh1, acc[1][1], 0, 0, 0);
        }
        if (t16 < 15) {
          __syncthreads();
          STORE(buf ^ 1);
          __syncthreads();
        }
      }
#undef FRAG

      #pragma unroll
      for (int mi = 0; mi < 2; mi++) {
        #pragma unroll
        for (int i = 0; i < 4; i++) {
          int grow = bi * 64 + wr * 32 + mi * 16 + rowg * 4 + i;
          u64 key = 0;
          #pragma unroll
          for (int ni = 0; ni < 2; ni++) {
            int gcol = bj * 64 + wc * 32 + ni * 16 + colg;
            if (gcol < n2) {
              u64 k2 = packKey(acc[mi][ni][i], gcol);
              if (k2 > key) key = k2;
            }
          }
          #pragma unroll
          for (int m = 8; m; m >>= 1) {
            u64 o = (u64)__shfl_xor((long long)key, m, 64);
            if (o > key) key = o;
          }
          if (colg == 0 && grow < mid && key) atomicMax(&ws->bestKey[grow], key);
        }
      }
    }
  }
  grid.sync();

  // ================= P5: match (block 0 only) =================
  if (bid == 0) {
    int* flag = (int*)lds;
    int* mwsum = flag + N;
    #pragma unroll
    for (int q = 0; q < 16; q++) flag[tid * 16 + q] = 0;
    __syncthreads();
    #pragma unroll
    for (int q = 0; q < 8; q++) {
      int r = tid + q * 256;
      if (r < mid) {
        int j = (int)(~(unsigned)(ws->bestKey[r] & 0xffffffffull));
        ws->matches[r] = j;
        flag[j] = 1;   // benign race: same value
      }
    }
    __syncthreads();
    int v[8], loc[8]; int tot = 0;
    #pragma unroll
    for (int q = 0; q < 8; q++) {
      int j = tid * 8 + q;
      bool val = (j < n2) && (flag[j] == 0);
      v[q] = val; loc[q] = tot; tot += (int)val;
    }
    int inc = tot;
    #pragma unroll
    for (int o = 1; o < 64; o <<= 1) { int u = __shfl_up(inc, o, 64); if (lane >= o) inc += u; }
    if (lane == 63) mwsum[wv] = inc;
    __syncthreads();
    if (tid == 0) { mwsum[1] += mwsum[0]; mwsum[2] += mwsum[1]; mwsum[3] += mwsum[2]; }
    __syncthreads();
    int base = (wv ? mwsum[wv - 1] : 0) + inc - tot;
    #pragma unroll
    for (int q = 0; q < 8; q++)
      if (v[q]) ws->residIdx[base + loc[q]] = ws->A2idx[tid * 8 + q];
    if (tid == 0) ws->n_resid = mwsum[3];
  }
  grid.sync();

  // ================= P6: write output =================
  {
    int n_B = ws->n_B, n_resid = ws->n_resid;
    #pragma unroll 1
    for (int it = 0; it < 32; it++) {
      int r = it * 256 + bid;
      float4 res = make_float4(0.f, 0.f, 0.f, 0.f);
      if (r < N) {
        if (r < n_B) {
          res = ((const float4*)(x + (size_t)ws->Bidx[r] * D))[tid];
        } else if (r < n_B + mid) {
          int m = r - n_B;
          float4 v1 = ((const float4*)(x + (size_t)ws->A1idx[m] * D))[tid];
          float4 v2 = ((const float4*)(x + (size_t)ws->A2idx[ws->matches[m]] * D))[tid];
          res = make_float4(0.5f * (v1.x + v2.x), 0.5f * (v1.y + v2.y),
                            0.5f * (v1.z + v2.z), 0.5f * (v1.w + v2.w));
        }
      } else {
        int k = r - N;
        if (k < n_resid) {
          res = ((const float4*)(x + (size_t)ws->residIdx[k] * D))[tid];
        }
      }
      ((float4*)(out + (size_t)r * D))[tid] = res;
    }
  }
}

extern "C" void kernel_launch(void* const* d_in, const int* in_sizes, int n_in,
                              void* d_out, int out_size, void* d_ws, size_t ws_size,
                              hipStream_t stream) {
  const float* x = (const float*)d_in[0];
  const float* attn = (const float*)d_in[1];
  float* out = (float*)d_out;
  WS* ws = (WS*)d_ws;
  // d_out (33.5 MB) doubles as scratch for the tiled packed f16 planes (16 MB);
  // P6 fully overwrites it after the P4->P5 grid syncs.
  f16* PAhi = (f16*)d_out;
  f16* PAlo = PAhi + PLANE;
  f16* PBhi = PAlo + PLANE;
  f16* PBlo = PBhi + PLANE;

  void* args[8] = {(void*)&x, (void*)&attn, (void*)&PAhi, (void*)&PAlo,
                   (void*)&PBhi, (void*)&PBlo, (void*)&out, (void*)&ws};
  hipLaunchCooperativeKernel((void*)k_all, dim3(256), dim3(256), args, 0, stream);
}

// Round 13
// 146.461 us; speedup vs baseline: 1.3319x; 1.3319x over previous
//
#include <hip/hip_runtime.h>

#define N 4096
#define D 1024
#define EPSF 1e-6f

typedef _Float16 f16;
typedef f16 f16x8 __attribute__((ext_vector_type(8)));
typedef float f32x4 __attribute__((ext_vector_type(4)));
typedef unsigned long long u64;

#define PLANE ((size_t)2048 * 1024)  // f16 elements per packed plane

struct WS {
  unsigned c1, c2, c3, c4;   // RESET TO 0 BY hipMemsetAsync EVERY LAUNCH
  int n_A, mid, n2, n_B, n_resid, pad[3];
  float a[N];
  float diag[N];
  int A1idx[N];
  int A2idx[N];
  int Bidx[N];
  int matches[N];
  int residIdx[N];
  u64 bestKey[2048];
};

__device__ __forceinline__ u64 packKey(float v, int j) {
  unsigned u = __float_as_uint(v);
  unsigned m = (u & 0x80000000u) ? ~u : (u | 0x80000000u);
  return ((u64)m << 32) | (unsigned)(~(unsigned)j);
}

// ===== K1: per-row prep; the TRUE last-arriving block (counter reset to 0
// this launch) runs the round-11-verified mask. a/diag published and read
// via device-scope RMW atomics (coherence-point on both sides). =====
__global__ __launch_bounds__(256) void k_prep(const float* __restrict__ x,
                                              const float* __restrict__ attn, WS* ws) {
  int row = blockIdx.x;
  int tid = threadIdx.x;
  int lane = tid & 63, wv = tid >> 6;
  __shared__ float w[4];
  __shared__ int slast;

  float4 v = ((const float4*)(x + (size_t)row * D))[tid];
  float sm = v.x + v.y + v.z + v.w;
  for (int o = 32; o; o >>= 1) sm += __shfl_down(sm, o, 64);
  if (lane == 0) w[wv] = sm;
  __syncthreads();
  if (tid == 0) {
    float am = (w[0] + w[1] + w[2] + w[3]) * (1.0f / D);
    atomicExch((unsigned*)&ws->a[row], __float_as_uint(am));
    atomicExch((unsigned*)&ws->diag[row], __float_as_uint(attn[(size_t)row * (N + 1)]));
    __threadfence();
    unsigned c = atomicAdd(&ws->c1, 1u);
    slast = (c == (unsigned)(N - 1));   // true chronological last (c1 == 0 at launch)
  }
  __syncthreads();
  if (!slast) return;

  // ---- fused mask (round-11 verified body; RMW payload reads) ----
  __shared__ double dred[4], dred2[4];
  __shared__ float bcast[2];
  __shared__ int hist[256];
  __shared__ int wsum[4];
  __shared__ unsigned sPrefix;
  __shared__ int sRank;

  // zero bestKey for gemm's atomicMax (crosses kernel boundary to K3)
  #pragma unroll
  for (int q = 0; q < 8; q++) ws->bestKey[tid * 8 + q] = 0ull;

  float av[16], dg[16];
  double s = 0.0, s2 = 0.0;
  #pragma unroll
  for (int q = 0; q < 16; q++) {
    int i = tid * 16 + q;
    av[q] = __uint_as_float(atomicOr((unsigned*)&ws->a[i], 0u));
    dg[q] = __uint_as_float(atomicOr((unsigned*)&ws->diag[i], 0u));
    s += av[q]; s2 += (double)av[q] * av[q];
  }
  for (int o = 32; o; o >>= 1) { s += __shfl_down(s, o, 64); s2 += __shfl_down(s2, o, 64); }
  if (lane == 0) { dred[wv] = s; dred2[wv] = s2; }
  __syncthreads();
  if (tid == 0) {
    double t1 = dred[0] + dred[1] + dred[2] + dred[3];
    double t2 = dred2[0] + dred2[1] + dred2[2] + dred2[3];
    bcast[0] = (float)(t1 / N);
    bcast[1] = (float)sqrt((t2 - t1 * t1 / N) / (N - 1));
  }
  __syncthreads();
  float meanA = bcast[0], stdA = bcast[1];

  float il[16];
  s = 0.0; s2 = 0.0;
  #pragma unroll
  for (int q = 0; q < 16; q++) {
    float z = (av[q] - meanA) / (stdA + EPSF);
    float I = z * z * dg[q];
    il[q] = I; s += I; s2 += (double)I * I;
  }
  for (int o = 32; o; o >>= 1) { s += __shfl_down(s, o, 64); s2 += __shfl_down(s2, o, 64); }
  __syncthreads();
  if (lane == 0) { dred[wv] = s; dred2[wv] = s2; }
  __syncthreads();
  if (tid == 0) {
    double t1 = dred[0] + dred[1] + dred[2] + dred[3];
    double t2 = dred2[0] + dred2[1] + dred2[2] + dred2[3];
    bcast[0] = (float)(t1 / N);
    bcast[1] = (float)sqrt((t2 - t1 * t1 / N) / (N - 1));
    sPrefix = 0u; sRank = (N - 1) / 2;
  }
  __syncthreads();
  float meanI = bcast[0], stdI = bcast[1];

  float sv[16]; unsigned ab[16];
  #pragma unroll
  for (int q = 0; q < 16; q++) {
    float sval = (il[q] - meanI) / (stdI + EPSF);
    sv[q] = sval;
    ab[q] = __float_as_uint(fabsf(sval));
  }

  for (int p = 3; p >= 0; p--) {
    hist[tid] = 0;
    __syncthreads();
    unsigned pre = sPrefix;
    int rk = sRank;
    int sh = p * 8;
    unsigned mHi = (p == 3) ? 0u : (0xFFFFFFFFu << (sh + 8));
    #pragma unroll
    for (int q = 0; q < 16; q++)
      if ((ab[q] & mHi) == pre) atomicAdd(&hist[(ab[q] >> sh) & 255], 1);
    __syncthreads();
    int v2 = hist[tid];
    int inc = v2;
    #pragma unroll
    for (int o = 1; o < 64; o <<= 1) { int u = __shfl_up(inc, o, 64); if (lane >= o) inc += u; }
    if (lane == 63) wsum[wv] = inc;
    __syncthreads();
    if (tid == 0) { wsum[1] += wsum[0]; wsum[2] += wsum[1]; wsum[3] += wsum[2]; }
    __syncthreads();
    int incl = (wv ? wsum[wv - 1] : 0) + inc;
    int E = incl - v2;
    if (v2 && rk >= E && rk < E + v2) {
      sPrefix = pre | ((unsigned)tid << sh);
      sRank = rk - E;
    }
    __syncthreads();
  }
  float med = __uint_as_float(sPrefix);

  int msk[16], loc[16]; int tot = 0;
  #pragma unroll
  for (int q = 0; q < 16; q++) {
    bool m = fabsf(sv[q]) > med;
    msk[q] = m; loc[q] = tot; tot += (int)m;
  }
  int inc = tot;
  #pragma unroll
  for (int o = 1; o < 64; o <<= 1) { int u = __shfl_up(inc, o, 64); if (lane >= o) inc += u; }
  if (lane == 63) wsum[wv] = inc;
  __syncthreads();
  if (tid == 0) { wsum[1] += wsum[0]; wsum[2] += wsum[1]; wsum[3] += wsum[2]; }
  __syncthreads();
  int nA = wsum[3];
  int base = (wv ? wsum[wv - 1] : 0) + inc - tot;
  int midl = nA >> 1;
  #pragma unroll
  for (int q = 0; q < 16; q++) {
    int i = tid * 16 + q;
    int r = base + loc[q];
    if (msk[q]) {
      if (r < midl) ws->A1idx[r] = i; else ws->A2idx[r - midl] = i;
    } else {
      ws->Bidx[i - r] = i;
    }
  }
  if (tid == 0) { ws->n_A = nA; ws->mid = midl; ws->n2 = nA - midl; ws->n_B = N - nA; }
}

// ===== K2: gather selected rows -> tiled swizzled f16 hi/lo planes (verbatim r7/r11) =====
__global__ __launch_bounds__(128) void k_pack(const float* __restrict__ x,
                                              f16* __restrict__ PAhi, f16* __restrict__ PAlo,
                                              f16* __restrict__ PBhi, f16* __restrict__ PBlo,
                                              WS* ws) {
  int b = blockIdx.x, t = threadIdx.x;
  const float* src;
  f16 *dh, *dl;
  int j;
  if (b < 2048) {
    if (b >= ws->mid) return;
    j = b;
    src = x + (size_t)ws->A1idx[b] * D;
    dh = PAhi; dl = PAlo;
  } else {
    j = b - 2048;
    if (j >= ws->n2) return;
    src = x + (size_t)ws->A2idx[j] * D;
    dh = PBhi; dl = PBlo;
  }
  float4 v0 = ((const float4*)src)[t * 2];
  float4 v1 = ((const float4*)src)[t * 2 + 1];
  float vv[8] = {v0.x, v0.y, v0.z, v0.w, v1.x, v1.y, v1.z, v1.w};
  f16x8 h, l;
  #pragma unroll
  for (int q = 0; q < 8; q++) {
    f16 hq = (f16)vv[q];
    h[q] = hq;
    l[q] = (f16)(vv[q] - (float)hq);
  }
  int rt = j >> 6, rl = j & 63;
  int kt = t >> 3, gl = t & 7;
  size_t off = ((size_t)(rt * 16 + kt) << 12) + rl * 64 + ((gl ^ (rl & 7)) * 8);
  *(f16x8*)(dh + off) = h;
  *(f16x8*)(dl + off) = l;
}

// ===== K3: gemm (validity-wrapped, NO early return) + TRUE-last-block match =====
__global__ __launch_bounds__(256) void k_gemm(const f16* __restrict__ PAhi,
                                              const f16* __restrict__ PAlo,
                                              const f16* __restrict__ PBhi,
                                              const f16* __restrict__ PBlo, WS* ws) {
  __shared__ __align__(16) f16 lds[2][4][64 * 64];  // 64 KiB; aliased by match phase
  __shared__ int isLast;

  const int mid = ws->mid, n2 = ws->n2;
  const int tid = threadIdx.x;
  const int lane = tid & 63;

  {
    int L = blockIdx.x;
    int local = L >> 3;
    int bj = ((L & 7) << 1) | (local >> 4);
    int bi = local & 15;
    if (bi * 64 < mid && bj * 64 < n2) {
      const int wid = tid >> 6;
      const int wr = wid >> 1, wc = wid & 1;
      const f16* plane = (wid == 0) ? PAhi : (wid == 1) ? PAlo : (wid == 2) ? PBhi : PBlo;
      const int ptile = (wid < 2) ? bi : bj;

      f16x8 pr[8];
      auto LOAD = [&](int t) {
        const f16* tb = plane + ((size_t)((ptile << 4) + t) << 12);
        #pragma unroll
        for (int i = 0; i < 8; i++) pr[i] = *(const f16x8*)(tb + i * 512 + lane * 8);
      };
      auto STORE = [&](int buf) {
        #pragma unroll
        for (int i = 0; i < 8; i++) *(f16x8*)&lds[buf][wid][i * 512 + lane * 8] = pr[i];
      };

      const int colg = lane & 15, rowg = lane >> 4;
      const int ma0 = wr * 32 + colg, ma1 = ma0 + 16;
      const int mb0 = wc * 32 + colg, mb1 = mb0 + 16;

      f32x4 zero = {0.f, 0.f, 0.f, 0.f};
      f32x4 acc[2][2];
      acc[0][0] = zero; acc[0][1] = zero; acc[1][0] = zero; acc[1][1] = zero;

#define FRAG(buf, t4, row, g) \
  (*(const f16x8*)&lds[buf][t4][(row) * 64 + ((((g) ^ ((row) & 7))) * 8)])

      LOAD(0);
      STORE(0);
      __syncthreads();
      #pragma unroll 1
      for (int t16 = 0; t16 < 16; t16++) {
        int buf = t16 & 1;
        if (t16 < 15) LOAD(t16 + 1);
        #pragma unroll
        for (int ks = 0; ks < 2; ks++) {
          int gk = ks * 4 + rowg;
          f16x8 ah0 = FRAG(buf, 0, ma0, gk), ah1 = FRAG(buf, 0, ma1, gk);
          f16x8 al0 = FRAG(buf, 1, ma0, gk), al1 = FRAG(buf, 1, ma1, gk);
          f16x8 bh0 = FRAG(buf, 2, mb0, gk), bh1 = FRAG(buf, 2, mb1, gk);
          f16x8 bl0 = FRAG(buf, 3, mb0, gk), bl1 = FRAG(buf, 3, mb1, gk);
          acc[0][0] = __builtin_amdgcn_mfma_f32_16x16x32_f16(ah0, bh0, acc[0][0], 0, 0, 0);
          acc[0][0] = __builtin_amdgcn_mfma_f32_16x16x32_f16(ah0, bl0, acc[0][0], 0, 0, 0);
          acc[0][0] = __builtin_amdgcn_mfma_f32_16x16x32_f16(al0, bh0, acc[0][0], 0, 0, 0);
          acc[0][1] = __builtin_amdgcn_mfma_f32_16x16x32_f16(ah0, bh1, acc[0][1], 0, 0, 0);
          acc[0][1] = __builtin_amdgcn_mfma_f32_16x16x32_f16(ah0, bl1, acc[0][1], 0, 0, 0);
          acc[0][1] = __builtin_amdgcn_mfma_f32_16x16x32_f16(al0, bh1, acc[0][1], 0, 0, 0);
          acc[1][0] = __builtin_amdgcn_mfma_f32_16x16x32_f16(ah1, bh0, acc[1][0], 0, 0, 0);
          acc[1][0] = __builtin_amdgcn_mfma_f32_16x16x32_f16(ah1, bl0, acc[1][0], 0, 0, 0);
          acc[1][0] = __builtin_amdgcn_mfma_f32_16x16x32_f16(al1, bh0, acc[1][0], 0, 0, 0);
          acc[1][1] = __builtin_amdgcn_mfma_f32_16x16x32_f16(ah1, bh1, acc[1][1], 0, 0, 0);
          acc[1][1] = __builtin_amdgcn_mfma_f32_16x16x32_f16(ah1, bl1, acc[1][1], 0, 0, 0);
          acc[1][1] = __builtin_amdgcn_mfma_f32_16x16x32_f16(al1, bh1, acc[1][1], 0, 0, 0);
        }
        if (t16 < 15) {
          __syncthreads();
          STORE(buf ^ 1);
          __syncthreads();
        }
      }
#undef FRAG

      #pragma unroll
      for (int mi = 0; mi < 2; mi++) {
        #pragma unroll
        for (int i = 0; i < 4; i++) {
          int grow = bi * 64 + wr * 32 + mi * 16 + rowg * 4 + i;
          u64 key = 0;
          #pragma unroll
          for (int ni = 0; ni < 2; ni++) {
            int gcol = bj * 64 + wc * 32 + ni * 16 + colg;
            if (gcol < n2) {
              u64 k2 = packKey(acc[mi][ni][i], gcol);
              if (k2 > key) key = k2;
            }
          }
          #pragma unroll
          for (int m = 8; m; m >>= 1) {
            u64 o = (u64)__shfl_xor((long long)key, m, 64);
            if (o > key) key = o;
          }
          if (colg == 0 && grow < mid && key) atomicMax(&ws->bestKey[grow], key);
        }
      }
    }
  }
  __syncthreads();
  if (tid == 0) {
    __threadfence();
    unsigned c = atomicAdd(&ws->c3, 1u);
    isLast = (c == 255u);   // true chronological last (c3 == 0 at launch)
  }
  __syncthreads();
  if (!isLast) return;

  // ---- match: decode bestKey (RMW reads) + residual compaction ----
  {
    int* flag = (int*)lds;
    int* mwsum = flag + N;
    int wv = tid >> 6;
    #pragma unroll
    for (int q = 0; q < 16; q++) flag[tid * 16 + q] = 0;
    __syncthreads();
    #pragma unroll
    for (int q = 0; q < 8; q++) {
      int r = tid + q * 256;
      if (r < mid) {
        u64 k = atomicMax(&ws->bestKey[r], 0ull);   // coherence-point read
        int j = (int)(~(unsigned)(k & 0xffffffffull));
        ws->matches[r] = j;
        flag[j] = 1;   // benign race: same value
      }
    }
    __syncthreads();
    int v[8], loc[8]; int tot = 0;
    #pragma unroll
    for (int q = 0; q < 8; q++) {
      int j = tid * 8 + q;
      bool val = (j < ws->n2) && (flag[j] == 0);
      v[q] = val; loc[q] = tot; tot += (int)val;
    }
    int inc = tot;
    #pragma unroll
    for (int o = 1; o < 64; o <<= 1) { int u = __shfl_up(inc, o, 64); if (lane >= o) inc += u; }
    if (lane == 63) mwsum[wv] = inc;
    __syncthreads();
    if (tid == 0) { mwsum[1] += mwsum[0]; mwsum[2] += mwsum[1]; mwsum[3] += mwsum[2]; }
    __syncthreads();
    int base = (wv ? mwsum[wv - 1] : 0) + inc - tot;
    #pragma unroll
    for (int q = 0; q < 8; q++)
      if (v[q]) ws->residIdx[base + loc[q]] = ws->A2idx[tid * 8 + q];
    if (tid == 0) ws->n_resid = mwsum[3];
  }
}

// ===== K4: one block per output row (verbatim r7/r11) =====
__global__ __launch_bounds__(256) void k_write(const float* __restrict__ x,
                                               float* __restrict__ out, WS* ws) {
  int r = blockIdx.x;
  int t = threadIdx.x;
  int n_B = ws->n_B, mid = ws->mid, n_resid = ws->n_resid;
  float4 res = make_float4(0.f, 0.f, 0.f, 0.f);
  if (r < N) {
    if (r < n_B) {
      res = ((const float4*)(x + (size_t)ws->Bidx[r] * D))[t];
    } else if (r < n_B + mid) {
      int m = r - n_B;
      float4 v1 = ((const float4*)(x + (size_t)ws->A1idx[m] * D))[t];
      float4 v2 = ((const float4*)(x + (size_t)ws->A2idx[ws->matches[m]] * D))[t];
      res = make_float4(0.5f * (v1.x + v2.x), 0.5f * (v1.y + v2.y),
                        0.5f * (v1.z + v2.z), 0.5f * (v1.w + v2.w));
    }
  } else {
    int k = r - N;
    if (k < n_resid) {
      res = ((const float4*)(x + (size_t)ws->residIdx[k] * D))[t];
    }
  }
  ((float4*)(out + (size_t)r * D))[t] = res;
}

extern "C" void kernel_launch(void* const* d_in, const int* in_sizes, int n_in,
                              void* d_out, int out_size, void* d_ws, size_t ws_size,
                              hipStream_t stream) {
  const float* x = (const float*)d_in[0];
  const float* attn = (const float*)d_in[1];
  float* out = (float*)d_out;
  WS* ws = (WS*)d_ws;
  // d_out (33.5 MB) doubles as scratch for the tiled packed f16 planes (16 MB);
  // k_write fully overwrites it afterwards (stream-ordered, deterministic).
  f16* PAhi = (f16*)d_out;
  f16* PAlo = PAhi + PLANE;
  f16* PBhi = PAlo + PLANE;
  f16* PBlo = PBhi + PLANE;

  // counters MUST start at 0 each launch for last-arrival detection
  hipMemsetAsync(&ws->c1, 0, 4 * sizeof(unsigned), stream);
  k_prep<<<N, 256, 0, stream>>>(x, attn, ws);
  k_pack<<<4096, 128, 0, stream>>>(x, PAhi, PAlo, PBhi, PBlo, ws);
  k_gemm<<<256, 256, 0, stream>>>(PAhi, PAlo, PBhi, PBlo, ws);
  k_write<<<2 * N, 256, 0, stream>>>(x, out, ws);
}

// Round 14
// 71.927 us; speedup vs baseline: 2.7121x; 2.0362x over previous
//
#include <hip/hip_runtime.h>

#define N 4096
#define D 1024
#define EPSF 1e-6f

typedef _Float16 f16;
typedef f16 f16x8 __attribute__((ext_vector_type(8)));
typedef float f32x4 __attribute__((ext_vector_type(4)));
typedef unsigned long long u64;

#define PLANE ((size_t)2048 * 1024)  // f16 elements per packed plane

struct WS {
  unsigned c1, c2, c3, c4;   // zeroed by hipMemsetAsync every launch
  int n_A, mid, n2, n_B, n_resid, pad[3];
  float a[N];
  float diag[N];
  int A1idx[N];
  int A2idx[N];
  int Bidx[N];
  int matches[N];
  int residIdx[N];
  u64 bestKey[2048];
};

__device__ __forceinline__ u64 packKey(float v, int j) {
  unsigned u = __float_as_uint(v);
  unsigned m = (u & 0x80000000u) ? ~u : (u | 0x80000000u);
  return ((u64)m << 32) | (unsigned)(~(unsigned)j);
}

// ===== K1: prep (256 blocks x 16 rows, r12-verified layout) + true-last-block
// mask (r13-verified body). RMW publish/read; NO threadfence — __syncthreads
// drains the exchs before the counter add. =====
__global__ __launch_bounds__(256) void k_pm(const float* __restrict__ x,
                                            const float* __restrict__ attn, WS* ws) {
  int tid = threadIdx.x;
  int lane = tid & 63, wv = tid >> 6;
  int bid = blockIdx.x;
  __shared__ int slast;

  #pragma unroll
  for (int rr = 0; rr < 4; rr++) {
    int row = bid * 16 + wv * 4 + rr;
    const float4* xr = (const float4*)(x + (size_t)row * D);
    float sm = 0.f;
    #pragma unroll
    for (int it = 0; it < 4; it++) {
      float4 v = xr[it * 64 + lane];
      sm += v.x + v.y + v.z + v.w;
    }
    for (int o = 32; o; o >>= 1) sm += __shfl_down(sm, o, 64);
    if (lane == 0) {
      atomicExch((unsigned*)&ws->a[row], __float_as_uint(sm * (1.0f / D)));
      atomicExch((unsigned*)&ws->diag[row], __float_as_uint(attn[(size_t)row * (N + 1)]));
    }
  }
  __syncthreads();                      // drains all exchs (vmcnt(0) before barrier)
  if (tid == 0) {
    unsigned c = atomicAdd(&ws->c1, 1u);
    slast = (c == 255u);                // true chronological last (c1==0 at launch)
  }
  __syncthreads();
  if (!slast) return;

  // ---- fused mask (r13-verified body; RMW payload reads) ----
  __shared__ double dred[4], dred2[4];
  __shared__ float bcast[2];
  __shared__ int hist[256];
  __shared__ int wsum[4];
  __shared__ unsigned sPrefix;
  __shared__ int sRank;

  #pragma unroll
  for (int q = 0; q < 8; q++) ws->bestKey[tid * 8 + q] = 0ull;

  float av[16], dg[16];
  double s = 0.0, s2 = 0.0;
  #pragma unroll
  for (int q = 0; q < 16; q++) {
    int i = tid * 16 + q;
    av[q] = __uint_as_float(atomicOr((unsigned*)&ws->a[i], 0u));
    dg[q] = __uint_as_float(atomicOr((unsigned*)&ws->diag[i], 0u));
    s += av[q]; s2 += (double)av[q] * av[q];
  }
  for (int o = 32; o; o >>= 1) { s += __shfl_down(s, o, 64); s2 += __shfl_down(s2, o, 64); }
  if (lane == 0) { dred[wv] = s; dred2[wv] = s2; }
  __syncthreads();
  if (tid == 0) {
    double t1 = dred[0] + dred[1] + dred[2] + dred[3];
    double t2 = dred2[0] + dred2[1] + dred2[2] + dred2[3];
    bcast[0] = (float)(t1 / N);
    bcast[1] = (float)sqrt((t2 - t1 * t1 / N) / (N - 1));
  }
  __syncthreads();
  float meanA = bcast[0], stdA = bcast[1];

  float il[16];
  s = 0.0; s2 = 0.0;
  #pragma unroll
  for (int q = 0; q < 16; q++) {
    float z = (av[q] - meanA) / (stdA + EPSF);
    float I = z * z * dg[q];
    il[q] = I; s += I; s2 += (double)I * I;
  }
  for (int o = 32; o; o >>= 1) { s += __shfl_down(s, o, 64); s2 += __shfl_down(s2, o, 64); }
  __syncthreads();
  if (lane == 0) { dred[wv] = s; dred2[wv] = s2; }
  __syncthreads();
  if (tid == 0) {
    double t1 = dred[0] + dred[1] + dred[2] + dred[3];
    double t2 = dred2[0] + dred2[1] + dred2[2] + dred2[3];
    bcast[0] = (float)(t1 / N);
    bcast[1] = (float)sqrt((t2 - t1 * t1 / N) / (N - 1));
    sPrefix = 0u; sRank = (N - 1) / 2;
  }
  __syncthreads();
  float meanI = bcast[0], stdI = bcast[1];

  float sv[16]; unsigned ab[16];
  #pragma unroll
  for (int q = 0; q < 16; q++) {
    float sval = (il[q] - meanI) / (stdI + EPSF);
    sv[q] = sval;
    ab[q] = __float_as_uint(fabsf(sval));
  }

  for (int p = 3; p >= 0; p--) {
    hist[tid] = 0;
    __syncthreads();
    unsigned pre = sPrefix;
    int rk = sRank;
    int sh = p * 8;
    unsigned mHi = (p == 3) ? 0u : (0xFFFFFFFFu << (sh + 8));
    #pragma unroll
    for (int q = 0; q < 16; q++)
      if ((ab[q] & mHi) == pre) atomicAdd(&hist[(ab[q] >> sh) & 255], 1);
    __syncthreads();
    int v2 = hist[tid];
    int inc = v2;
    #pragma unroll
    for (int o = 1; o < 64; o <<= 1) { int u = __shfl_up(inc, o, 64); if (lane >= o) inc += u; }
    if (lane == 63) wsum[wv] = inc;
    __syncthreads();
    if (tid == 0) { wsum[1] += wsum[0]; wsum[2] += wsum[1]; wsum[3] += wsum[2]; }
    __syncthreads();
    int incl = (wv ? wsum[wv - 1] : 0) + inc;
    int E = incl - v2;
    if (v2 && rk >= E && rk < E + v2) {
      sPrefix = pre | ((unsigned)tid << sh);
      sRank = rk - E;
    }
    __syncthreads();
  }
  float med = __uint_as_float(sPrefix);

  int msk[16], loc[16]; int tot = 0;
  #pragma unroll
  for (int q = 0; q < 16; q++) {
    bool m = fabsf(sv[q]) > med;
    msk[q] = m; loc[q] = tot; tot += (int)m;
  }
  int inc = tot;
  #pragma unroll
  for (int o = 1; o < 64; o <<= 1) { int u = __shfl_up(inc, o, 64); if (lane >= o) inc += u; }
  if (lane == 63) wsum[wv] = inc;
  __syncthreads();
  if (tid == 0) { wsum[1] += wsum[0]; wsum[2] += wsum[1]; wsum[3] += wsum[2]; }
  __syncthreads();
  int nA = wsum[3];
  int base = (wv ? wsum[wv - 1] : 0) + inc - tot;
  int midl = nA >> 1;
  #pragma unroll
  for (int q = 0; q < 16; q++) {
    int i = tid * 16 + q;
    int r = base + loc[q];
    if (msk[q]) {
      if (r < midl) ws->A1idx[r] = i; else ws->A2idx[r - midl] = i;
    } else {
      ws->Bidx[i - r] = i;
    }
  }
  if (tid == 0) { ws->n_A = nA; ws->mid = midl; ws->n2 = nA - midl; ws->n_B = N - nA; }
}

// ===== K2: gather selected rows -> tiled swizzled f16 hi/lo planes (r11 verbatim) =====
__global__ __launch_bounds__(128) void k_pack(const float* __restrict__ x,
                                              f16* __restrict__ PAhi, f16* __restrict__ PAlo,
                                              f16* __restrict__ PBhi, f16* __restrict__ PBlo,
                                              WS* ws) {
  int b = blockIdx.x, t = threadIdx.x;
  const float* src;
  f16 *dh, *dl;
  int j;
  if (b < 2048) {
    if (b >= ws->mid) return;
    j = b;
    src = x + (size_t)ws->A1idx[b] * D;
    dh = PAhi; dl = PAlo;
  } else {
    j = b - 2048;
    if (j >= ws->n2) return;
    src = x + (size_t)ws->A2idx[j] * D;
    dh = PBhi; dl = PBlo;
  }
  float4 v0 = ((const float4*)src)[t * 2];
  float4 v1 = ((const float4*)src)[t * 2 + 1];
  float vv[8] = {v0.x, v0.y, v0.z, v0.w, v1.x, v1.y, v1.z, v1.w};
  f16x8 h, l;
  #pragma unroll
  for (int q = 0; q < 8; q++) {
    f16 hq = (f16)vv[q];
    h[q] = hq;
    l[q] = (f16)(vv[q] - (float)hq);
  }
  int rt = j >> 6, rl = j & 63;
  int kt = t >> 3, gl = t & 7;
  size_t off = ((size_t)(rt * 16 + kt) << 12) + rl * 64 + ((gl ^ (rl & 7)) * 8);
  *(f16x8*)(dh + off) = h;
  *(f16x8*)(dl + off) = l;
}

// ===== K3: gemm -> true-last-block match (RMW publish) -> all-block write =====
__global__ __launch_bounds__(256) void k_fused(const float* __restrict__ x,
                                               const f16* __restrict__ PAhi,
                                               const f16* __restrict__ PAlo,
                                               const f16* __restrict__ PBhi,
                                               const f16* __restrict__ PBlo,
                                               float* __restrict__ out, WS* ws) {
  __shared__ __align__(16) f16 lds[2][4][64 * 64];  // 64 KiB; aliased by match/write
  __shared__ int isLast;

  const int mid = ws->mid, n2 = ws->n2;
  const int tid = threadIdx.x;
  const int lane = tid & 63;
  const int bid = blockIdx.x;

  // ---- gemm (r13 verbatim, validity-wrapped, no early return) ----
  {
    int local = bid >> 3;
    int bj = ((bid & 7) << 1) | (local >> 4);
    int bi = local & 15;
    if (bi * 64 < mid && bj * 64 < n2) {
      const int wid = tid >> 6;
      const int wr = wid >> 1, wc = wid & 1;
      const f16* plane = (wid == 0) ? PAhi : (wid == 1) ? PAlo : (wid == 2) ? PBhi : PBlo;
      const int ptile = (wid < 2) ? bi : bj;

      f16x8 pr[8];
      auto LOAD = [&](int t) {
        const f16* tb = plane + ((size_t)((ptile << 4) + t) << 12);
        #pragma unroll
        for (int i = 0; i < 8; i++) pr[i] = *(const f16x8*)(tb + i * 512 + lane * 8);
      };
      auto STORE = [&](int buf) {
        #pragma unroll
        for (int i = 0; i < 8; i++) *(f16x8*)&lds[buf][wid][i * 512 + lane * 8] = pr[i];
      };

      const int colg = lane & 15, rowg = lane >> 4;
      const int ma0 = wr * 32 + colg, ma1 = ma0 + 16;
      const int mb0 = wc * 32 + colg, mb1 = mb0 + 16;

      f32x4 zero = {0.f, 0.f, 0.f, 0.f};
      f32x4 acc[2][2];
      acc[0][0] = zero; acc[0][1] = zero; acc[1][0] = zero; acc[1][1] = zero;

#define FRAG(buf, t4, row, g) \
  (*(const f16x8*)&lds[buf][t4][(row) * 64 + ((((g) ^ ((row) & 7))) * 8)])

      LOAD(0);
      STORE(0);
      __syncthreads();
      #pragma unroll 1
      for (int t16 = 0; t16 < 16; t16++) {
        int buf = t16 & 1;
        if (t16 < 15) LOAD(t16 + 1);
        #pragma unroll
        for (int ks = 0; ks < 2; ks++) {
          int gk = ks * 4 + rowg;
          f16x8 ah0 = FRAG(buf, 0, ma0, gk), ah1 = FRAG(buf, 0, ma1, gk);
          f16x8 al0 = FRAG(buf, 1, ma0, gk), al1 = FRAG(buf, 1, ma1, gk);
          f16x8 bh0 = FRAG(buf, 2, mb0, gk), bh1 = FRAG(buf, 2, mb1, gk);
          f16x8 bl0 = FRAG(buf, 3, mb0, gk), bl1 = FRAG(buf, 3, mb1, gk);
          acc[0][0] = __builtin_amdgcn_mfma_f32_16x16x32_f16(ah0, bh0, acc[0][0], 0, 0, 0);
          acc[0][0] = __builtin_amdgcn_mfma_f32_16x16x32_f16(ah0, bl0, acc[0][0], 0, 0, 0);
          acc[0][0] = __builtin_amdgcn_mfma_f32_16x16x32_f16(al0, bh0, acc[0][0], 0, 0, 0);
          acc[0][1] = __builtin_amdgcn_mfma_f32_16x16x32_f16(ah0, bh1, acc[0][1], 0, 0, 0);
          acc[0][1] = __builtin_amdgcn_mfma_f32_16x16x32_f16(ah0, bl1, acc[0][1], 0, 0, 0);
          acc[0][1] = __builtin_amdgcn_mfma_f32_16x16x32_f16(al0, bh1, acc[0][1], 0, 0, 0);
          acc[1][0] = __builtin_amdgcn_mfma_f32_16x16x32_f16(ah1, bh0, acc[1][0], 0, 0, 0);
          acc[1][0] = __builtin_amdgcn_mfma_f32_16x16x32_f16(ah1, bl0, acc[1][0], 0, 0, 0);
          acc[1][0] = __builtin_amdgcn_mfma_f32_16x16x32_f16(al1, bh0, acc[1][0], 0, 0, 0);
          acc[1][1] = __builtin_amdgcn_mfma_f32_16x16x32_f16(ah1, bh1, acc[1][1], 0, 0, 0);
          acc[1][1] = __builtin_amdgcn_mfma_f32_16x16x32_f16(ah1, bl1, acc[1][1], 0, 0, 0);
          acc[1][1] = __builtin_amdgcn_mfma_f32_16x16x32_f16(al1, bh1, acc[1][1], 0, 0, 0);
        }
        if (t16 < 15) {
          __syncthreads();
          STORE(buf ^ 1);
          __syncthreads();
        }
      }
#undef FRAG

      #pragma unroll
      for (int mi = 0; mi < 2; mi++) {
        #pragma unroll
        for (int i = 0; i < 4; i++) {
          int grow = bi * 64 + wr * 32 + mi * 16 + rowg * 4 + i;
          u64 key = 0;
          #pragma unroll
          for (int ni = 0; ni < 2; ni++) {
            int gcol = bj * 64 + wc * 32 + ni * 16 + colg;
            if (gcol < n2) {
              u64 k2 = packKey(acc[mi][ni][i], gcol);
              if (k2 > key) key = k2;
            }
          }
          #pragma unroll
          for (int m = 8; m; m >>= 1) {
            u64 o = (u64)__shfl_xor((long long)key, m, 64);
            if (o > key) key = o;
          }
          if (colg == 0 && grow < mid && key) atomicMax(&ws->bestKey[grow], key);
        }
      }
    }
  }
  __syncthreads();                 // drains this block's atomicMaxes
  if (tid == 0) {
    unsigned c = atomicAdd(&ws->c3, 1u);
    isLast = (c == 255u);
  }
  __syncthreads();

  // ---- match: last block decodes bestKey, publishes via RMW ----
  if (isLast) {
    int* flag = (int*)lds;
    int* mwsum = flag + N;
    int wv = tid >> 6;
    #pragma unroll
    for (int q = 0; q < 16; q++) flag[tid * 16 + q] = 0;
    __syncthreads();
    #pragma unroll
    for (int q = 0; q < 8; q++) {
      int r = tid + q * 256;
      if (r < mid) {
        u64 k = atomicMax(&ws->bestKey[r], 0ull);
        int j = (int)(~(unsigned)(k & 0xffffffffull));
        atomicExch((unsigned*)&ws->matches[r], (unsigned)j);
        flag[j] = 1;   // benign race: same value
      }
    }
    __syncthreads();
    int v[8], loc[8]; int tot = 0;
    #pragma unroll
    for (int q = 0; q < 8; q++) {
      int j = tid * 8 + q;
      bool val = (j < n2) && (flag[j] == 0);
      v[q] = val; loc[q] = tot; tot += (int)val;
    }
    int inc = tot;
    #pragma unroll
    for (int o = 1; o < 64; o <<= 1) { int u = __shfl_up(inc, o, 64); if (lane >= o) inc += u; }
    if (lane == 63) mwsum[wv] = inc;
    __syncthreads();
    if (tid == 0) { mwsum[1] += mwsum[0]; mwsum[2] += mwsum[1]; mwsum[3] += mwsum[2]; }
    __syncthreads();
    int base = (wv ? mwsum[wv - 1] : 0) + inc - tot;
    #pragma unroll
    for (int q = 0; q < 8; q++)
      if (v[q]) atomicExch((unsigned*)&ws->residIdx[base + loc[q]],
                           (unsigned)ws->A2idx[tid * 8 + q]);
    if (tid == 0) atomicExch((unsigned*)&ws->n_resid, (unsigned)mwsum[3]);
    __syncthreads();               // drains all match exchs
    if (tid == 0) atomicExch(&ws->c4, 1u);
  } else {
    if (tid == 0) {
      while (atomicAdd(&ws->c4, 0u) == 0u) __builtin_amdgcn_s_sleep(4);
    }
  }
  __syncthreads();

  // ---- write: prefetch per-row metadata via RMW, then r9-audited loop ----
  {
    int* wsh = ((int*)lds) + 8192;   // dead LDS region post-match
    int n_B = ws->n_B;
    if (tid == 0) wsh[0] = (int)atomicOr((unsigned*)&ws->n_resid, 0u);
    __syncthreads();
    int n_resid = wsh[0];
    if (tid < 32) {
      int r = tid * 256 + bid;
      int val = 0;
      if (r < N) {
        if (r >= n_B && r < n_B + mid)
          val = (int)atomicOr((unsigned*)&ws->matches[r - n_B], 0u);
      } else {
        int k = r - N;
        if (k < n_resid)
          val = (int)atomicOr((unsigned*)&ws->residIdx[k], 0u);
      }
      wsh[1 + tid] = val;
    }
    __syncthreads();
    #pragma unroll 1
    for (int it = 0; it < 32; it++) {
      int r = it * 256 + bid;
      float4 res = make_float4(0.f, 0.f, 0.f, 0.f);
      if (r < N) {
        if (r < n_B) {
          res = ((const float4*)(x + (size_t)ws->Bidx[r] * D))[tid];
        } else if (r < n_B + mid) {
          int m = r - n_B;
          float4 v1 = ((const float4*)(x + (size_t)ws->A1idx[m] * D))[tid];
          float4 v2 = ((const float4*)(x + (size_t)ws->A2idx[wsh[1 + it]] * D))[tid];
          res = make_float4(0.5f * (v1.x + v2.x), 0.5f * (v1.y + v2.y),
                            0.5f * (v1.z + v2.z), 0.5f * (v1.w + v2.w));
        }
      } else {
        int k = r - N;
        if (k < n_resid) {
          res = ((const float4*)(x + (size_t)wsh[1 + it] * D))[tid];
        }
      }
      ((float4*)(out + (size_t)r * D))[tid] = res;
    }
  }
}

extern "C" void kernel_launch(void* const* d_in, const int* in_sizes, int n_in,
                              void* d_out, int out_size, void* d_ws, size_t ws_size,
                              hipStream_t stream) {
  const float* x = (const float*)d_in[0];
  const float* attn = (const float*)d_in[1];
  float* out = (float*)d_out;
  WS* ws = (WS*)d_ws;
  // d_out (33.5 MB) doubles as scratch for the tiled packed f16 planes (16 MB);
  // K3's write phase fully overwrites it (post-gemm, barrier-ordered).
  f16* PAhi = (f16*)d_out;
  f16* PAlo = PAhi + PLANE;
  f16* PBhi = PAlo + PLANE;
  f16* PBlo = PBhi + PLANE;

  hipMemsetAsync(&ws->c1, 0, 4 * sizeof(unsigned), stream);  // counters = 0 each launch
  k_pm<<<256, 256, 0, stream>>>(x, attn, ws);
  k_pack<<<4096, 128, 0, stream>>>(x, PAhi, PAlo, PBhi, PBlo, ws);
  k_fused<<<256, 256, 0, stream>>>(x, PAhi, PAlo, PBhi, PBlo, out, ws);
}

// Round 15
// 67.411 us; speedup vs baseline: 2.8937x; 1.0670x over previous
//
#include <hip/hip_runtime.h>

#define N 4096
#define D 1024
#define EPSF 1e-6f

typedef _Float16 f16;
typedef f16 f16x8 __attribute__((ext_vector_type(8)));
typedef float f32x4 __attribute__((ext_vector_type(4)));
typedef unsigned long long u64;

#define PLANE ((size_t)2048 * 1024)  // f16 elements per packed plane

struct WS {
  unsigned c1, c2, c3, c4;   // zeroed by hipMemsetAsync every launch
  int n_A, mid, n2, n_B, n_resid, pad[3];
  float a[N];
  float diag[N];
  int A1idx[N];
  int A2idx[N];
  int Bidx[N];
  int matches[N];
  int residIdx[N];
  u64 bestKey[2048];
};

__device__ __forceinline__ u64 packKey(float v, int j) {
  unsigned u = __float_as_uint(v);
  unsigned m = (u & 0x80000000u) ? ~u : (u | 0x80000000u);
  return ((u64)m << 32) | (unsigned)(~(unsigned)j);
}

// ===== K1: prep (256 blocks x 16 rows) + true-last-block mask (r14 verbatim,
// verified passing). RMW publish/read; no threadfence. =====
__global__ __launch_bounds__(256) void k_pm(const float* __restrict__ x,
                                            const float* __restrict__ attn, WS* ws) {
  int tid = threadIdx.x;
  int lane = tid & 63, wv = tid >> 6;
  int bid = blockIdx.x;
  __shared__ int slast;

  #pragma unroll
  for (int rr = 0; rr < 4; rr++) {
    int row = bid * 16 + wv * 4 + rr;
    const float4* xr = (const float4*)(x + (size_t)row * D);
    float sm = 0.f;
    #pragma unroll
    for (int it = 0; it < 4; it++) {
      float4 v = xr[it * 64 + lane];
      sm += v.x + v.y + v.z + v.w;
    }
    for (int o = 32; o; o >>= 1) sm += __shfl_down(sm, o, 64);
    if (lane == 0) {
      atomicExch((unsigned*)&ws->a[row], __float_as_uint(sm * (1.0f / D)));
      atomicExch((unsigned*)&ws->diag[row], __float_as_uint(attn[(size_t)row * (N + 1)]));
    }
  }
  __syncthreads();                      // drains all exchs (vmcnt(0) before barrier)
  if (tid == 0) {
    unsigned c = atomicAdd(&ws->c1, 1u);
    slast = (c == 255u);                // true chronological last (c1==0 at launch)
  }
  __syncthreads();
  if (!slast) return;

  // ---- fused mask (RMW payload reads) ----
  __shared__ double dred[4], dred2[4];
  __shared__ float bcast[2];
  __shared__ int hist[256];
  __shared__ int wsum[4];
  __shared__ unsigned sPrefix;
  __shared__ int sRank;

  #pragma unroll
  for (int q = 0; q < 8; q++) ws->bestKey[tid * 8 + q] = 0ull;

  float av[16], dg[16];
  double s = 0.0, s2 = 0.0;
  #pragma unroll
  for (int q = 0; q < 16; q++) {
    int i = tid * 16 + q;
    av[q] = __uint_as_float(atomicOr((unsigned*)&ws->a[i], 0u));
    dg[q] = __uint_as_float(atomicOr((unsigned*)&ws->diag[i], 0u));
    s += av[q]; s2 += (double)av[q] * av[q];
  }
  for (int o = 32; o; o >>= 1) { s += __shfl_down(s, o, 64); s2 += __shfl_down(s2, o, 64); }
  if (lane == 0) { dred[wv] = s; dred2[wv] = s2; }
  __syncthreads();
  if (tid == 0) {
    double t1 = dred[0] + dred[1] + dred[2] + dred[3];
    double t2 = dred2[0] + dred2[1] + dred2[2] + dred2[3];
    bcast[0] = (float)(t1 / N);
    bcast[1] = (float)sqrt((t2 - t1 * t1 / N) / (N - 1));
  }
  __syncthreads();
  float meanA = bcast[0], stdA = bcast[1];

  float il[16];
  s = 0.0; s2 = 0.0;
  #pragma unroll
  for (int q = 0; q < 16; q++) {
    float z = (av[q] - meanA) / (stdA + EPSF);
    float I = z * z * dg[q];
    il[q] = I; s += I; s2 += (double)I * I;
  }
  for (int o = 32; o; o >>= 1) { s += __shfl_down(s, o, 64); s2 += __shfl_down(s2, o, 64); }
  __syncthreads();
  if (lane == 0) { dred[wv] = s; dred2[wv] = s2; }
  __syncthreads();
  if (tid == 0) {
    double t1 = dred[0] + dred[1] + dred[2] + dred[3];
    double t2 = dred2[0] + dred2[1] + dred2[2] + dred2[3];
    bcast[0] = (float)(t1 / N);
    bcast[1] = (float)sqrt((t2 - t1 * t1 / N) / (N - 1));
    sPrefix = 0u; sRank = (N - 1) / 2;
  }
  __syncthreads();
  float meanI = bcast[0], stdI = bcast[1];

  float sv[16]; unsigned ab[16];
  #pragma unroll
  for (int q = 0; q < 16; q++) {
    float sval = (il[q] - meanI) / (stdI + EPSF);
    sv[q] = sval;
    ab[q] = __float_as_uint(fabsf(sval));
  }

  for (int p = 3; p >= 0; p--) {
    hist[tid] = 0;
    __syncthreads();
    unsigned pre = sPrefix;
    int rk = sRank;
    int sh = p * 8;
    unsigned mHi = (p == 3) ? 0u : (0xFFFFFFFFu << (sh + 8));
    #pragma unroll
    for (int q = 0; q < 16; q++)
      if ((ab[q] & mHi) == pre) atomicAdd(&hist[(ab[q] >> sh) & 255], 1);
    __syncthreads();
    int v2 = hist[tid];
    int inc = v2;
    #pragma unroll
    for (int o = 1; o < 64; o <<= 1) { int u = __shfl_up(inc, o, 64); if (lane >= o) inc += u; }
    if (lane == 63) wsum[wv] = inc;
    __syncthreads();
    if (tid == 0) { wsum[1] += wsum[0]; wsum[2] += wsum[1]; wsum[3] += wsum[2]; }
    __syncthreads();
    int incl = (wv ? wsum[wv - 1] : 0) + inc;
    int E = incl - v2;
    if (v2 && rk >= E && rk < E + v2) {
      sPrefix = pre | ((unsigned)tid << sh);
      sRank = rk - E;
    }
    __syncthreads();
  }
  float med = __uint_as_float(sPrefix);

  int msk[16], loc[16]; int tot = 0;
  #pragma unroll
  for (int q = 0; q < 16; q++) {
    bool m = fabsf(sv[q]) > med;
    msk[q] = m; loc[q] = tot; tot += (int)m;
  }
  int inc = tot;
  #pragma unroll
  for (int o = 1; o < 64; o <<= 1) { int u = __shfl_up(inc, o, 64); if (lane >= o) inc += u; }
  if (lane == 63) wsum[wv] = inc;
  __syncthreads();
  if (tid == 0) { wsum[1] += wsum[0]; wsum[2] += wsum[1]; wsum[3] += wsum[2]; }
  __syncthreads();
  int nA = wsum[3];
  int base = (wv ? wsum[wv - 1] : 0) + inc - tot;
  int midl = nA >> 1;
  #pragma unroll
  for (int q = 0; q < 16; q++) {
    int i = tid * 16 + q;
    int r = base + loc[q];
    if (msk[q]) {
      if (r < midl) ws->A1idx[r] = i; else ws->A2idx[r - midl] = i;
    } else {
      ws->Bidx[i - r] = i;
    }
  }
  if (tid == 0) { ws->n_A = nA; ws->mid = midl; ws->n2 = nA - midl; ws->n_B = N - nA; }
}

// ===== K2: gather selected rows -> tiled swizzled f16 hi/lo planes (verbatim) =====
__global__ __launch_bounds__(128) void k_pack(const float* __restrict__ x,
                                              f16* __restrict__ PAhi, f16* __restrict__ PAlo,
                                              f16* __restrict__ PBhi, f16* __restrict__ PBlo,
                                              WS* ws) {
  int b = blockIdx.x, t = threadIdx.x;
  const float* src;
  f16 *dh, *dl;
  int j;
  if (b < 2048) {
    if (b >= ws->mid) return;
    j = b;
    src = x + (size_t)ws->A1idx[b] * D;
    dh = PAhi; dl = PAlo;
  } else {
    j = b - 2048;
    if (j >= ws->n2) return;
    src = x + (size_t)ws->A2idx[j] * D;
    dh = PBhi; dl = PBlo;
  }
  float4 v0 = ((const float4*)src)[t * 2];
  float4 v1 = ((const float4*)src)[t * 2 + 1];
  float vv[8] = {v0.x, v0.y, v0.z, v0.w, v1.x, v1.y, v1.z, v1.w};
  f16x8 h, l;
  #pragma unroll
  for (int q = 0; q < 8; q++) {
    f16 hq = (f16)vv[q];
    h[q] = hq;
    l[q] = (f16)(vv[q] - (float)hq);
  }
  int rt = j >> 6, rl = j & 63;
  int kt = t >> 3, gl = t & 7;
  size_t off = ((size_t)(rt * 16 + kt) << 12) + rl * 64 + ((gl ^ (rl & 7)) * 8);
  *(f16x8*)(dh + off) = h;
  *(f16x8*)(dl + off) = l;
}

// ===== K3: gemm + TRUE-last-block match, no spin (r13 verbatim, verified) =====
__global__ __launch_bounds__(256) void k_gemm(const f16* __restrict__ PAhi,
                                              const f16* __restrict__ PAlo,
                                              const f16* __restrict__ PBhi,
                                              const f16* __restrict__ PBlo, WS* ws) {
  __shared__ __align__(16) f16 lds[2][4][64 * 64];  // 64 KiB; aliased by match phase
  __shared__ int isLast;

  const int mid = ws->mid, n2 = ws->n2;
  const int tid = threadIdx.x;
  const int lane = tid & 63;

  {
    int L = blockIdx.x;
    int local = L >> 3;
    int bj = ((L & 7) << 1) | (local >> 4);
    int bi = local & 15;
    if (bi * 64 < mid && bj * 64 < n2) {
      const int wid = tid >> 6;
      const int wr = wid >> 1, wc = wid & 1;
      const f16* plane = (wid == 0) ? PAhi : (wid == 1) ? PAlo : (wid == 2) ? PBhi : PBlo;
      const int ptile = (wid < 2) ? bi : bj;

      f16x8 pr[8];
      auto LOAD = [&](int t) {
        const f16* tb = plane + ((size_t)((ptile << 4) + t) << 12);
        #pragma unroll
        for (int i = 0; i < 8; i++) pr[i] = *(const f16x8*)(tb + i * 512 + lane * 8);
      };
      auto STORE = [&](int buf) {
        #pragma unroll
        for (int i = 0; i < 8; i++) *(f16x8*)&lds[buf][wid][i * 512 + lane * 8] = pr[i];
      };

      const int colg = lane & 15, rowg = lane >> 4;
      const int ma0 = wr * 32 + colg, ma1 = ma0 + 16;
      const int mb0 = wc * 32 + colg, mb1 = mb0 + 16;

      f32x4 zero = {0.f, 0.f, 0.f, 0.f};
      f32x4 acc[2][2];
      acc[0][0] = zero; acc[0][1] = zero; acc[1][0] = zero; acc[1][1] = zero;

#define FRAG(buf, t4, row, g) \
  (*(const f16x8*)&lds[buf][t4][(row) * 64 + ((((g) ^ ((row) & 7))) * 8)])

      LOAD(0);
      STORE(0);
      __syncthreads();
      #pragma unroll 1
      for (int t16 = 0; t16 < 16; t16++) {
        int buf = t16 & 1;
        if (t16 < 15) LOAD(t16 + 1);
        #pragma unroll
        for (int ks = 0; ks < 2; ks++) {
          int gk = ks * 4 + rowg;
          f16x8 ah0 = FRAG(buf, 0, ma0, gk), ah1 = FRAG(buf, 0, ma1, gk);
          f16x8 al0 = FRAG(buf, 1, ma0, gk), al1 = FRAG(buf, 1, ma1, gk);
          f16x8 bh0 = FRAG(buf, 2, mb0, gk), bh1 = FRAG(buf, 2, mb1, gk);
          f16x8 bl0 = FRAG(buf, 3, mb0, gk), bl1 = FRAG(buf, 3, mb1, gk);
          acc[0][0] = __builtin_amdgcn_mfma_f32_16x16x32_f16(ah0, bh0, acc[0][0], 0, 0, 0);
          acc[0][0] = __builtin_amdgcn_mfma_f32_16x16x32_f16(ah0, bl0, acc[0][0], 0, 0, 0);
          acc[0][0] = __builtin_amdgcn_mfma_f32_16x16x32_f16(al0, bh0, acc[0][0], 0, 0, 0);
          acc[0][1] = __builtin_amdgcn_mfma_f32_16x16x32_f16(ah0, bh1, acc[0][1], 0, 0, 0);
          acc[0][1] = __builtin_amdgcn_mfma_f32_16x16x32_f16(ah0, bl1, acc[0][1], 0, 0, 0);
          acc[0][1] = __builtin_amdgcn_mfma_f32_16x16x32_f16(al0, bh1, acc[0][1], 0, 0, 0);
          acc[1][0] = __builtin_amdgcn_mfma_f32_16x16x32_f16(ah1, bh0, acc[1][0], 0, 0, 0);
          acc[1][0] = __builtin_amdgcn_mfma_f32_16x16x32_f16(ah1, bl0, acc[1][0], 0, 0, 0);
          acc[1][0] = __builtin_amdgcn_mfma_f32_16x16x32_f16(al1, bh0, acc[1][0], 0, 0, 0);
          acc[1][1] = __builtin_amdgcn_mfma_f32_16x16x32_f16(ah1, bh1, acc[1][1], 0, 0, 0);
          acc[1][1] = __builtin_amdgcn_mfma_f32_16x16x32_f16(ah1, bl1, acc[1][1], 0, 0, 0);
          acc[1][1] = __builtin_amdgcn_mfma_f32_16x16x32_f16(al1, bh1, acc[1][1], 0, 0, 0);
        }
        if (t16 < 15) {
          __syncthreads();
          STORE(buf ^ 1);
          __syncthreads();
        }
      }
#undef FRAG

      #pragma unroll
      for (int mi = 0; mi < 2; mi++) {
        #pragma unroll
        for (int i = 0; i < 4; i++) {
          int grow = bi * 64 + wr * 32 + mi * 16 + rowg * 4 + i;
          u64 key = 0;
          #pragma unroll
          for (int ni = 0; ni < 2; ni++) {
            int gcol = bj * 64 + wc * 32 + ni * 16 + colg;
            if (gcol < n2) {
              u64 k2 = packKey(acc[mi][ni][i], gcol);
              if (k2 > key) key = k2;
            }
          }
          #pragma unroll
          for (int m = 8; m; m >>= 1) {
            u64 o = (u64)__shfl_xor((long long)key, m, 64);
            if (o > key) key = o;
          }
          if (colg == 0 && grow < mid && key) atomicMax(&ws->bestKey[grow], key);
        }
      }
    }
  }
  __syncthreads();               // drains this block's atomicMaxes
  if (tid == 0) {
    unsigned c = atomicAdd(&ws->c3, 1u);
    isLast = (c == 255u);        // true chronological last (c3==0 at launch)
  }
  __syncthreads();
  if (!isLast) return;           // non-last blocks exit; NO spin

  // ---- match: decode bestKey (RMW reads) + residual compaction ----
  {
    int* flag = (int*)lds;
    int* mwsum = flag + N;
    int wv = tid >> 6;
    #pragma unroll
    for (int q = 0; q < 16; q++) flag[tid * 16 + q] = 0;
    __syncthreads();
    #pragma unroll
    for (int q = 0; q < 8; q++) {
      int r = tid + q * 256;
      if (r < mid) {
        u64 k = atomicMax(&ws->bestKey[r], 0ull);   // coherence-point read
        int j = (int)(~(unsigned)(k & 0xffffffffull));
        ws->matches[r] = j;       // crosses kernel boundary to k_write
        flag[j] = 1;              // benign race: same value
      }
    }
    __syncthreads();
    int v[8], loc[8]; int tot = 0;
    #pragma unroll
    for (int q = 0; q < 8; q++) {
      int j = tid * 8 + q;
      bool val = (j < ws->n2) && (flag[j] == 0);
      v[q] = val; loc[q] = tot; tot += (int)val;
    }
    int inc = tot;
    #pragma unroll
    for (int o = 1; o < 64; o <<= 1) { int u = __shfl_up(inc, o, 64); if (lane >= o) inc += u; }
    if (lane == 63) mwsum[wv] = inc;
    __syncthreads();
    if (tid == 0) { mwsum[1] += mwsum[0]; mwsum[2] += mwsum[1]; mwsum[3] += mwsum[2]; }
    __syncthreads();
    int base = (wv ? mwsum[wv - 1] : 0) + inc - tot;
    #pragma unroll
    for (int q = 0; q < 8; q++)
      if (v[q]) ws->residIdx[base + loc[q]] = ws->A2idx[tid * 8 + q];
    if (tid == 0) ws->n_resid = mwsum[3];
  }
}

// ===== K4: one block per output row, full occupancy (r13 verbatim, verified) =====
__global__ __launch_bounds__(256) void k_write(const float* __restrict__ x,
                                               float* __restrict__ out, WS* ws) {
  int r = blockIdx.x;
  int t = threadIdx.x;
  int n_B = ws->n_B, mid = ws->mid, n_resid = ws->n_resid;
  float4 res = make_float4(0.f, 0.f, 0.f, 0.f);
  if (r < N) {
    if (r < n_B) {
      res = ((const float4*)(x + (size_t)ws->Bidx[r] * D))[t];
    } else if (r < n_B + mid) {
      int m = r - n_B;
      float4 v1 = ((const float4*)(x + (size_t)ws->A1idx[m] * D))[t];
      float4 v2 = ((const float4*)(x + (size_t)ws->A2idx[ws->matches[m]] * D))[t];
      res = make_float4(0.5f * (v1.x + v2.x), 0.5f * (v1.y + v2.y),
                        0.5f * (v1.z + v2.z), 0.5f * (v1.w + v2.w));
    }
  } else {
    int k = r - N;
    if (k < n_resid) {
      res = ((const float4*)(x + (size_t)ws->residIdx[k] * D))[t];
    }
  }
  ((float4*)(out + (size_t)r * D))[t] = res;
}

extern "C" void kernel_launch(void* const* d_in, const int* in_sizes, int n_in,
                              void* d_out, int out_size, void* d_ws, size_t ws_size,
                              hipStream_t stream) {
  const float* x = (const float*)d_in[0];
  const float* attn = (const float*)d_in[1];
  float* out = (float*)d_out;
  WS* ws = (WS*)d_ws;
  // d_out (33.5 MB) doubles as scratch for the tiled packed f16 planes (16 MB);
  // k_write fully overwrites it afterwards (stream-ordered, deterministic).
  f16* PAhi = (f16*)d_out;
  f16* PAlo = PAhi + PLANE;
  f16* PBhi = PAlo + PLANE;
  f16* PBlo = PBhi + PLANE;

  hipMemsetAsync(&ws->c1, 0, 4 * sizeof(unsigned), stream);  // counters = 0 each launch
  k_pm<<<256, 256, 0, stream>>>(x, attn, ws);
  k_pack<<<4096, 128, 0, stream>>>(x, PAhi, PAlo, PBhi, PBlo, ws);
  k_gemm<<<256, 256, 0, stream>>>(PAhi, PAlo, PBhi, PBlo, ws);
  k_write<<<2 * N, 256, 0, stream>>>(x, out, ws);
}

// Round 16
// 66.218 us; speedup vs baseline: 2.9459x; 1.0180x over previous
//
#include <hip/hip_runtime.h>

#define N 4096
#define D 1024
#define EPSF 1e-6f

typedef _Float16 f16;
typedef f16 f16x8 __attribute__((ext_vector_type(8)));
typedef float f32x4 __attribute__((ext_vector_type(4)));
typedef unsigned long long u64;

#define PLANE ((size_t)2048 * 1024)  // f16 elements per packed plane

struct WS {
  unsigned c1, c2, c3, c4;   // zeroed by hipMemsetAsync every launch
  int n_A, mid, n2, n_B, n_resid, pad[3];
  float a[N];
  float diag[N];
  int A1idx[N];
  int A2idx[N];
  int Bidx[N];
  int matches[N];
  int residIdx[N];
  u64 bestKey[2048];
};

__device__ __forceinline__ u64 packKey(float v, int j) {
  unsigned u = __float_as_uint(v);
  unsigned m = (u & 0x80000000u) ? ~u : (u | 0x80000000u);
  return ((u64)m << 32) | (unsigned)(~(unsigned)j);
}

// ===== K1: prep (256 blocks x 1024 thr, 1 row/wave) + true-last-block mask
// at 1024 THREADS (r7-verified body; 4 elems/thread; RMW payload reads). =====
__global__ __launch_bounds__(1024) void k_pm(const float* __restrict__ x,
                                             const float* __restrict__ attn, WS* ws) {
  int tid = threadIdx.x;
  int lane = tid & 63, wv = tid >> 6;
  int bid = blockIdx.x;
  __shared__ int slast;

  // ---- prep: wave wv owns row bid*16 + wv ----
  {
    int row = bid * 16 + wv;
    const float4* xr = (const float4*)(x + (size_t)row * D);
    float sm = 0.f;
    #pragma unroll
    for (int it = 0; it < 4; it++) {
      float4 v = xr[it * 64 + lane];
      sm += v.x + v.y + v.z + v.w;
    }
    for (int o = 32; o; o >>= 1) sm += __shfl_down(sm, o, 64);
    if (lane == 0) {
      atomicExch((unsigned*)&ws->a[row], __float_as_uint(sm * (1.0f / D)));
      atomicExch((unsigned*)&ws->diag[row], __float_as_uint(attn[(size_t)row * (N + 1)]));
    }
  }
  __syncthreads();                      // drains exchs (vmcnt(0) before barrier)
  if (tid == 0) {
    unsigned c = atomicAdd(&ws->c1, 1u);
    slast = (c == 255u);                // true chronological last (c1==0 at launch)
  }
  __syncthreads();
  if (!slast) return;

  // ---- fused mask, 1024 threads, 4 elems/thread (r7-verified machinery) ----
  __shared__ double dred[16], dred2[16];
  __shared__ float bcast[2];
  __shared__ int hist[256];
  __shared__ int wsum[16];
  __shared__ unsigned sPrefix;
  __shared__ int sRank;

  ws->bestKey[tid] = 0ull;
  ws->bestKey[tid + 1024] = 0ull;

  // payload reads: device-scope RMW (coherence point)
  float av[4], dg[4];
  double s = 0.0, s2 = 0.0;
  #pragma unroll
  for (int q = 0; q < 4; q++) {
    int i = tid * 4 + q;
    av[q] = __uint_as_float(atomicOr((unsigned*)&ws->a[i], 0u));
    dg[q] = __uint_as_float(atomicOr((unsigned*)&ws->diag[i], 0u));
    s += av[q]; s2 += (double)av[q] * av[q];
  }
  for (int o = 32; o; o >>= 1) { s += __shfl_down(s, o, 64); s2 += __shfl_down(s2, o, 64); }
  if (lane == 0) { dred[wv] = s; dred2[wv] = s2; }
  __syncthreads();
  if (tid == 0) {
    double t1 = 0, t2 = 0;
    for (int i = 0; i < 16; i++) { t1 += dred[i]; t2 += dred2[i]; }
    bcast[0] = (float)(t1 / N);
    bcast[1] = (float)sqrt((t2 - t1 * t1 / N) / (N - 1));
  }
  __syncthreads();
  float meanA = bcast[0], stdA = bcast[1];

  float il[4];
  s = 0.0; s2 = 0.0;
  #pragma unroll
  for (int q = 0; q < 4; q++) {
    float z = (av[q] - meanA) / (stdA + EPSF);
    float I = z * z * dg[q];
    il[q] = I; s += I; s2 += (double)I * I;
  }
  for (int o = 32; o; o >>= 1) { s += __shfl_down(s, o, 64); s2 += __shfl_down(s2, o, 64); }
  __syncthreads();
  if (lane == 0) { dred[wv] = s; dred2[wv] = s2; }
  __syncthreads();
  if (tid == 0) {
    double t1 = 0, t2 = 0;
    for (int i = 0; i < 16; i++) { t1 += dred[i]; t2 += dred2[i]; }
    bcast[0] = (float)(t1 / N);
    bcast[1] = (float)sqrt((t2 - t1 * t1 / N) / (N - 1));
    sPrefix = 0u; sRank = (N - 1) / 2;
  }
  __syncthreads();
  float meanI = bcast[0], stdI = bcast[1];

  float sv[4]; unsigned ab[4];
  #pragma unroll
  for (int q = 0; q < 4; q++) {
    float sval = (il[q] - meanI) / (stdI + EPSF);
    sv[q] = sval;
    ab[q] = __float_as_uint(fabsf(sval));
  }

  // radix select rank-2047 of |s| bit patterns (4 passes, parallel bucket find)
  for (int p = 3; p >= 0; p--) {
    if (tid < 256) hist[tid] = 0;
    __syncthreads();
    unsigned pre = sPrefix;
    int rk = sRank;
    int sh = p * 8;
    unsigned mHi = (p == 3) ? 0u : (0xFFFFFFFFu << (sh + 8));
    #pragma unroll
    for (int q = 0; q < 4; q++)
      if ((ab[q] & mHi) == pre) atomicAdd(&hist[(ab[q] >> sh) & 255], 1);
    __syncthreads();
    int v = (tid < 256) ? hist[tid] : 0;
    int inc = v;
    #pragma unroll
    for (int o = 1; o < 64; o <<= 1) { int u = __shfl_up(inc, o, 64); if (lane >= o) inc += u; }
    if (lane == 63) wsum[wv] = inc;
    __syncthreads();
    if (tid < 16) {
      int t = wsum[tid];
      #pragma unroll
      for (int o = 1; o < 16; o <<= 1) { int u = __shfl_up(t, o, 64); if (tid >= o) t += u; }
      wsum[tid] = t;
    }
    __syncthreads();
    int incl = (wv ? wsum[wv - 1] : 0) + inc;
    int E = incl - v;
    if (tid < 256 && v && rk >= E && rk < E + v) {
      sPrefix = pre | ((unsigned)tid << sh);
      sRank = rk - E;
    }
    __syncthreads();
  }
  float med = __uint_as_float(sPrefix);

  // mask (strict |s| > med, bit-exact) + stable compaction (wave scan)
  int msk[4], loc[4]; int tot = 0;
  #pragma unroll
  for (int q = 0; q < 4; q++) {
    bool m = fabsf(sv[q]) > med;
    msk[q] = m; loc[q] = tot; tot += (int)m;
  }
  int inc = tot;
  #pragma unroll
  for (int o = 1; o < 64; o <<= 1) { int u = __shfl_up(inc, o, 64); if (lane >= o) inc += u; }
  if (lane == 63) wsum[wv] = inc;
  __syncthreads();
  if (tid < 16) {
    int t = wsum[tid];
    #pragma unroll
    for (int o = 1; o < 16; o <<= 1) { int u = __shfl_up(t, o, 64); if (tid >= o) t += u; }
    wsum[tid] = t;
  }
  __syncthreads();
  int nA = wsum[15];
  int base = (wv ? wsum[wv - 1] : 0) + inc - tot;
  int midl = nA >> 1;
  #pragma unroll
  for (int q = 0; q < 4; q++) {
    int i = tid * 4 + q;
    int r = base + loc[q];
    if (msk[q]) {
      if (r < midl) ws->A1idx[r] = i; else ws->A2idx[r - midl] = i;
    } else {
      ws->Bidx[i - r] = i;
    }
  }
  if (tid == 0) { ws->n_A = nA; ws->mid = midl; ws->n2 = nA - midl; ws->n_B = N - nA; }
}

// ===== K2: gather selected rows -> tiled swizzled f16 hi/lo planes (verbatim) =====
__global__ __launch_bounds__(128) void k_pack(const float* __restrict__ x,
                                              f16* __restrict__ PAhi, f16* __restrict__ PAlo,
                                              f16* __restrict__ PBhi, f16* __restrict__ PBlo,
                                              WS* ws) {
  int b = blockIdx.x, t = threadIdx.x;
  const float* src;
  f16 *dh, *dl;
  int j;
  if (b < 2048) {
    if (b >= ws->mid) return;
    j = b;
    src = x + (size_t)ws->A1idx[b] * D;
    dh = PAhi; dl = PAlo;
  } else {
    j = b - 2048;
    if (j >= ws->n2) return;
    src = x + (size_t)ws->A2idx[j] * D;
    dh = PBhi; dl = PBlo;
  }
  float4 v0 = ((const float4*)src)[t * 2];
  float4 v1 = ((const float4*)src)[t * 2 + 1];
  float vv[8] = {v0.x, v0.y, v0.z, v0.w, v1.x, v1.y, v1.z, v1.w};
  f16x8 h, l;
  #pragma unroll
  for (int q = 0; q < 8; q++) {
    f16 hq = (f16)vv[q];
    h[q] = hq;
    l[q] = (f16)(vv[q] - (float)hq);
  }
  int rt = j >> 6, rl = j & 63;
  int kt = t >> 3, gl = t & 7;
  size_t off = ((size_t)(rt * 16 + kt) << 12) + rl * 64 + ((gl ^ (rl & 7)) * 8);
  *(f16x8*)(dh + off) = h;
  *(f16x8*)(dl + off) = l;
}

// ===== K3: gemm + TRUE-last-block match, no spin (r15 verbatim, verified) =====
__global__ __launch_bounds__(256) void k_gemm(const f16* __restrict__ PAhi,
                                              const f16* __restrict__ PAlo,
                                              const f16* __restrict__ PBhi,
                                              const f16* __restrict__ PBlo, WS* ws) {
  __shared__ __align__(16) f16 lds[2][4][64 * 64];  // 64 KiB; aliased by match phase
  __shared__ int isLast;

  const int mid = ws->mid, n2 = ws->n2;
  const int tid = threadIdx.x;
  const int lane = tid & 63;

  {
    int L = blockIdx.x;
    int local = L >> 3;
    int bj = ((L & 7) << 1) | (local >> 4);
    int bi = local & 15;
    if (bi * 64 < mid && bj * 64 < n2) {
      const int wid = tid >> 6;
      const int wr = wid >> 1, wc = wid & 1;
      const f16* plane = (wid == 0) ? PAhi : (wid == 1) ? PAlo : (wid == 2) ? PBhi : PBlo;
      const int ptile = (wid < 2) ? bi : bj;

      f16x8 pr[8];
      auto LOAD = [&](int t) {
        const f16* tb = plane + ((size_t)((ptile << 4) + t) << 12);
        #pragma unroll
        for (int i = 0; i < 8; i++) pr[i] = *(const f16x8*)(tb + i * 512 + lane * 8);
      };
      auto STORE = [&](int buf) {
        #pragma unroll
        for (int i = 0; i < 8; i++) *(f16x8*)&lds[buf][wid][i * 512 + lane * 8] = pr[i];
      };

      const int colg = lane & 15, rowg = lane >> 4;
      const int ma0 = wr * 32 + colg, ma1 = ma0 + 16;
      const int mb0 = wc * 32 + colg, mb1 = mb0 + 16;

      f32x4 zero = {0.f, 0.f, 0.f, 0.f};
      f32x4 acc[2][2];
      acc[0][0] = zero; acc[0][1] = zero; acc[1][0] = zero; acc[1][1] = zero;

#define FRAG(buf, t4, row, g) \
  (*(const f16x8*)&lds[buf][t4][(row) * 64 + ((((g) ^ ((row) & 7))) * 8)])

      LOAD(0);
      STORE(0);
      __syncthreads();
      #pragma unroll 1
      for (int t16 = 0; t16 < 16; t16++) {
        int buf = t16 & 1;
        if (t16 < 15) LOAD(t16 + 1);
        #pragma unroll
        for (int ks = 0; ks < 2; ks++) {
          int gk = ks * 4 + rowg;
          f16x8 ah0 = FRAG(buf, 0, ma0, gk), ah1 = FRAG(buf, 0, ma1, gk);
          f16x8 al0 = FRAG(buf, 1, ma0, gk), al1 = FRAG(buf, 1, ma1, gk);
          f16x8 bh0 = FRAG(buf, 2, mb0, gk), bh1 = FRAG(buf, 2, mb1, gk);
          f16x8 bl0 = FRAG(buf, 3, mb0, gk), bl1 = FRAG(buf, 3, mb1, gk);
          acc[0][0] = __builtin_amdgcn_mfma_f32_16x16x32_f16(ah0, bh0, acc[0][0], 0, 0, 0);
          acc[0][0] = __builtin_amdgcn_mfma_f32_16x16x32_f16(ah0, bl0, acc[0][0], 0, 0, 0);
          acc[0][0] = __builtin_amdgcn_mfma_f32_16x16x32_f16(al0, bh0, acc[0][0], 0, 0, 0);
          acc[0][1] = __builtin_amdgcn_mfma_f32_16x16x32_f16(ah0, bh1, acc[0][1], 0, 0, 0);
          acc[0][1] = __builtin_amdgcn_mfma_f32_16x16x32_f16(ah0, bl1, acc[0][1], 0, 0, 0);
          acc[0][1] = __builtin_amdgcn_mfma_f32_16x16x32_f16(al0, bh1, acc[0][1], 0, 0, 0);
          acc[1][0] = __builtin_amdgcn_mfma_f32_16x16x32_f16(ah1, bh0, acc[1][0], 0, 0, 0);
          acc[1][0] = __builtin_amdgcn_mfma_f32_16x16x32_f16(ah1, bl0, acc[1][0], 0, 0, 0);
          acc[1][0] = __builtin_amdgcn_mfma_f32_16x16x32_f16(al1, bh0, acc[1][0], 0, 0, 0);
          acc[1][1] = __builtin_amdgcn_mfma_f32_16x16x32_f16(ah1, bh1, acc[1][1], 0, 0, 0);
          acc[1][1] = __builtin_amdgcn_mfma_f32_16x16x32_f16(ah1, bl1, acc[1][1], 0, 0, 0);
          acc[1][1] = __builtin_amdgcn_mfma_f32_16x16x32_f16(al1, bh1, acc[1][1], 0, 0, 0);
        }
        if (t16 < 15) {
          __syncthreads();
          STORE(buf ^ 1);
          __syncthreads();
        }
      }
#undef FRAG

      #pragma unroll
      for (int mi = 0; mi < 2; mi++) {
        #pragma unroll
        for (int i = 0; i < 4; i++) {
          int grow = bi * 64 + wr * 32 + mi * 16 + rowg * 4 + i;
          u64 key = 0;
          #pragma unroll
          for (int ni = 0; ni < 2; ni++) {
            int gcol = bj * 64 + wc * 32 + ni * 16 + colg;
            if (gcol < n2) {
              u64 k2 = packKey(acc[mi][ni][i], gcol);
              if (k2 > key) key = k2;
            }
          }
          #pragma unroll
          for (int m = 8; m; m >>= 1) {
            u64 o = (u64)__shfl_xor((long long)key, m, 64);
            if (o > key) key = o;
          }
          if (colg == 0 && grow < mid && key) atomicMax(&ws->bestKey[grow], key);
        }
      }
    }
  }
  __syncthreads();               // drains this block's atomicMaxes
  if (tid == 0) {
    unsigned c = atomicAdd(&ws->c3, 1u);
    isLast = (c == 255u);        // true chronological last (c3==0 at launch)
  }
  __syncthreads();
  if (!isLast) return;           // non-last blocks exit; NO spin

  // ---- match: decode bestKey (RMW reads) + residual compaction ----
  {
    int* flag = (int*)lds;
    int* mwsum = flag + N;
    int wv = tid >> 6;
    #pragma unroll
    for (int q = 0; q < 16; q++) flag[tid * 16 + q] = 0;
    __syncthreads();
    #pragma unroll
    for (int q = 0; q < 8; q++) {
      int r = tid + q * 256;
      if (r < mid) {
        u64 k = atomicMax(&ws->bestKey[r], 0ull);   // coherence-point read
        int j = (int)(~(unsigned)(k & 0xffffffffull));
        ws->matches[r] = j;       // crosses kernel boundary to k_write
        flag[j] = 1;              // benign race: same value
      }
    }
    __syncthreads();
    int v[8], loc[8]; int tot = 0;
    #pragma unroll
    for (int q = 0; q < 8; q++) {
      int j = tid * 8 + q;
      bool val = (j < ws->n2) && (flag[j] == 0);
      v[q] = val; loc[q] = tot; tot += (int)val;
    }
    int inc = tot;
    #pragma unroll
    for (int o = 1; o < 64; o <<= 1) { int u = __shfl_up(inc, o, 64); if (lane >= o) inc += u; }
    if (lane == 63) mwsum[wv] = inc;
    __syncthreads();
    if (tid == 0) { mwsum[1] += mwsum[0]; mwsum[2] += mwsum[1]; mwsum[3] += mwsum[2]; }
    __syncthreads();
    int base = (wv ? mwsum[wv - 1] : 0) + inc - tot;
    #pragma unroll
    for (int q = 0; q < 8; q++)
      if (v[q]) ws->residIdx[base + loc[q]] = ws->A2idx[tid * 8 + q];
    if (tid == 0) ws->n_resid = mwsum[3];
  }
}

// ===== K4: one block per output row, full occupancy (verbatim, verified) =====
__global__ __launch_bounds__(256) void k_write(const float* __restrict__ x,
                                               float* __restrict__ out, WS* ws) {
  int r = blockIdx.x;
  int t = threadIdx.x;
  int n_B = ws->n_B, mid = ws->mid, n_resid = ws->n_resid;
  float4 res = make_float4(0.f, 0.f, 0.f, 0.f);
  if (r < N) {
    if (r < n_B) {
      res = ((const float4*)(x + (size_t)ws->Bidx[r] * D))[t];
    } else if (r < n_B + mid) {
      int m = r - n_B;
      float4 v1 = ((const float4*)(x + (size_t)ws->A1idx[m] * D))[t];
      float4 v2 = ((const float4*)(x + (size_t)ws->A2idx[ws->matches[m]] * D))[t];
      res = make_float4(0.5f * (v1.x + v2.x), 0.5f * (v1.y + v2.y),
                        0.5f * (v1.z + v2.z), 0.5f * (v1.w + v2.w));
    }
  } else {
    int k = r - N;
    if (k < n_resid) {
      res = ((const float4*)(x + (size_t)ws->residIdx[k] * D))[t];
    }
  }
  ((float4*)(out + (size_t)r * D))[t] = res;
}

extern "C" void kernel_launch(void* const* d_in, const int* in_sizes, int n_in,
                              void* d_out, int out_size, void* d_ws, size_t ws_size,
                              hipStream_t stream) {
  const float* x = (const float*)d_in[0];
  const float* attn = (const float*)d_in[1];
  float* out = (float*)d_out;
  WS* ws = (WS*)d_ws;
  // d_out (33.5 MB) doubles as scratch for the tiled packed f16 planes (16 MB);
  // k_write fully overwrites it afterwards (stream-ordered, deterministic).
  f16* PAhi = (f16*)d_out;
  f16* PAlo = PAhi + PLANE;
  f16* PBhi = PAlo + PLANE;
  f16* PBlo = PBhi + PLANE;

  hipMemsetAsync(&ws->c1, 0, 4 * sizeof(unsigned), stream);  // counters = 0 each launch
  k_pm<<<256, 1024, 0, stream>>>(x, attn, ws);
  k_pack<<<4096, 128, 0, stream>>>(x, PAhi, PAlo, PBhi, PBlo, ws);
  k_gemm<<<256, 256, 0, stream>>>(PAhi, PAlo, PBhi, PBlo, ws);
  k_write<<<2 * N, 256, 0, stream>>>(x, out, ws);
}

// Round 17
// 58.287 us; speedup vs baseline: 3.3467x; 1.1361x over previous
//
#include <hip/hip_runtime.h>

#define N 4096
#define D 1024
#define EPSF 1e-6f

typedef _Float16 f16;
typedef f16 f16x8 __attribute__((ext_vector_type(8)));
typedef float f32x4 __attribute__((ext_vector_type(4)));
typedef unsigned long long u64;

#define PLANE ((size_t)2048 * 1024)  // f16 elements per packed plane

struct WS {
  unsigned c3, pad0[3];      // zeroed by k_mask every launch (boundary-coherent)
  int n_A, mid, n2, n_B, n_resid, pad[3];
  float a[N];
  float diag[N];
  int A1idx[N];
  int A2idx[N];
  int Bidx[N];
  int matches[N];
  int residIdx[N];
  u64 bestKey[2048];
};

__device__ __forceinline__ u64 packKey(float v, int j) {
  unsigned u = __float_as_uint(v);
  unsigned m = (u & 0x80000000u) ? ~u : (u | 0x80000000u);
  return ((u64)m << 32) | (unsigned)(~(unsigned)j);
}

// ===== K1: row means of x + attn diagonal (r11 verbatim; plain stores,
// kernel-boundary coherence — verified r2..r16) =====
__global__ __launch_bounds__(256) void k_prep(const float* __restrict__ x,
                                              const float* __restrict__ attn, WS* ws) {
  int row = blockIdx.x;
  int t = threadIdx.x;
  float4 v = ((const float4*)(x + (size_t)row * D))[t];
  float sm = v.x + v.y + v.z + v.w;
  for (int o = 32; o; o >>= 1) sm += __shfl_down(sm, o, 64);
  __shared__ float w[4];
  if ((t & 63) == 0) w[t >> 6] = sm;
  __syncthreads();
  if (t == 0) {
    ws->a[row] = (w[0] + w[1] + w[2] + w[3]) * (1.0f / D);
    ws->diag[row] = attn[(size_t)row * N + row];
  }
}

// ===== K2: fused mask, 1024 threads (r7 body verbatim — the amplification-
// verified 11.1us variant) + zeroes bestKey and c3 for K4's protocol =====
__global__ __launch_bounds__(1024) void k_mask(WS* ws) {
  __shared__ double dred[16], dred2[16];
  __shared__ float bcast[2];
  __shared__ int hist[256];
  __shared__ int wsum[16];
  __shared__ unsigned sPrefix;
  __shared__ int sRank;
  int tid = threadIdx.x;
  int lane = tid & 63, wv = tid >> 6;

  ws->bestKey[tid] = 0ull;
  ws->bestKey[tid + 1024] = 0ull;
  if (tid == 0) ws->c3 = 0u;

  // --- stats of a ---
  float av[4];
  double s = 0.0, s2 = 0.0;
  #pragma unroll
  for (int q = 0; q < 4; q++) {
    float f = ws->a[tid * 4 + q];
    av[q] = f; s += f; s2 += (double)f * f;
  }
  for (int o = 32; o; o >>= 1) { s += __shfl_down(s, o, 64); s2 += __shfl_down(s2, o, 64); }
  if (lane == 0) { dred[wv] = s; dred2[wv] = s2; }
  __syncthreads();
  if (tid == 0) {
    double t1 = 0, t2 = 0;
    for (int i = 0; i < 16; i++) { t1 += dred[i]; t2 += dred2[i]; }
    bcast[0] = (float)(t1 / N);
    bcast[1] = (float)sqrt((t2 - t1 * t1 / N) / (N - 1));
  }
  __syncthreads();
  float meanA = bcast[0], stdA = bcast[1];

  // --- Il = z^2 * diag, plus its stats ---
  float il[4];
  s = 0.0; s2 = 0.0;
  #pragma unroll
  for (int q = 0; q < 4; q++) {
    int i = tid * 4 + q;
    float z = (av[q] - meanA) / (stdA + EPSF);
    float I = z * z * ws->diag[i];
    il[q] = I; s += I; s2 += (double)I * I;
  }
  for (int o = 32; o; o >>= 1) { s += __shfl_down(s, o, 64); s2 += __shfl_down(s2, o, 64); }
  __syncthreads();
  if (lane == 0) { dred[wv] = s; dred2[wv] = s2; }
  __syncthreads();
  if (tid == 0) {
    double t1 = 0, t2 = 0;
    for (int i = 0; i < 16; i++) { t1 += dred[i]; t2 += dred2[i]; }
    bcast[0] = (float)(t1 / N);
    bcast[1] = (float)sqrt((t2 - t1 * t1 / N) / (N - 1));
    sPrefix = 0u; sRank = (N - 1) / 2;
  }
  __syncthreads();
  float meanI = bcast[0], stdI = bcast[1];

  float sv[4]; unsigned ab[4];
  #pragma unroll
  for (int q = 0; q < 4; q++) {
    float sval = (il[q] - meanI) / (stdI + EPSF);
    sv[q] = sval;
    ab[q] = __float_as_uint(fabsf(sval));
  }

  // --- radix select rank-2047 of |s| bit patterns (parallel bucket find) ---
  for (int p = 3; p >= 0; p--) {
    if (tid < 256) hist[tid] = 0;
    __syncthreads();
    unsigned pre = sPrefix;
    int rk = sRank;
    int sh = p * 8;
    unsigned mHi = (p == 3) ? 0u : (0xFFFFFFFFu << (sh + 8));
    #pragma unroll
    for (int q = 0; q < 4; q++)
      if ((ab[q] & mHi) == pre) atomicAdd(&hist[(ab[q] >> sh) & 255], 1);
    __syncthreads();
    int v = (tid < 256) ? hist[tid] : 0;
    int inc = v;
    #pragma unroll
    for (int o = 1; o < 64; o <<= 1) { int u = __shfl_up(inc, o, 64); if (lane >= o) inc += u; }
    if (lane == 63) wsum[wv] = inc;
    __syncthreads();
    if (tid < 16) {
      int t = wsum[tid];
      #pragma unroll
      for (int o = 1; o < 16; o <<= 1) { int u = __shfl_up(t, o, 64); if (tid >= o) t += u; }
      wsum[tid] = t;
    }
    __syncthreads();
    int incl = (wv ? wsum[wv - 1] : 0) + inc;
    int E = incl - v;
    if (tid < 256 && v && rk >= E && rk < E + v) {
      sPrefix = pre | ((unsigned)tid << sh);
      sRank = rk - E;
    }
    __syncthreads();
  }
  float med = __uint_as_float(sPrefix);

  // --- mask (strict |s| > med, bit-exact) + stable compaction (wave scan) ---
  int msk[4], loc[4]; int tot = 0;
  #pragma unroll
  for (int q = 0; q < 4; q++) {
    bool m = fabsf(sv[q]) > med;
    msk[q] = m; loc[q] = tot; tot += (int)m;
  }
  int inc = tot;
  #pragma unroll
  for (int o = 1; o < 64; o <<= 1) { int u = __shfl_up(inc, o, 64); if (lane >= o) inc += u; }
  if (lane == 63) wsum[wv] = inc;
  __syncthreads();
  if (tid < 16) {
    int t = wsum[tid];
    #pragma unroll
    for (int o = 1; o < 16; o <<= 1) { int u = __shfl_up(t, o, 64); if (tid >= o) t += u; }
    wsum[tid] = t;
  }
  __syncthreads();
  int nA = wsum[15];
  int base = (wv ? wsum[wv - 1] : 0) + inc - tot;
  int midl = nA >> 1;
  #pragma unroll
  for (int q = 0; q < 4; q++) {
    int i = tid * 4 + q;
    int r = base + loc[q];
    if (msk[q]) {
      if (r < midl) ws->A1idx[r] = i; else ws->A2idx[r - midl] = i;
    } else {
      ws->Bidx[i - r] = i;
    }
  }
  if (tid == 0) { ws->n_A = nA; ws->mid = midl; ws->n2 = nA - midl; ws->n_B = N - nA; }
}

// ===== K3: gather selected rows -> tiled swizzled f16 hi/lo planes (verbatim) =====
__global__ __launch_bounds__(128) void k_pack(const float* __restrict__ x,
                                              f16* __restrict__ PAhi, f16* __restrict__ PAlo,
                                              f16* __restrict__ PBhi, f16* __restrict__ PBlo,
                                              WS* ws) {
  int b = blockIdx.x, t = threadIdx.x;
  const float* src;
  f16 *dh, *dl;
  int j;
  if (b < 2048) {
    if (b >= ws->mid) return;
    j = b;
    src = x + (size_t)ws->A1idx[b] * D;
    dh = PAhi; dl = PAlo;
  } else {
    j = b - 2048;
    if (j >= ws->n2) return;
    src = x + (size_t)ws->A2idx[j] * D;
    dh = PBhi; dl = PBlo;
  }
  float4 v0 = ((const float4*)src)[t * 2];
  float4 v1 = ((const float4*)src)[t * 2 + 1];
  float vv[8] = {v0.x, v0.y, v0.z, v0.w, v1.x, v1.y, v1.z, v1.w};
  f16x8 h, l;
  #pragma unroll
  for (int q = 0; q < 8; q++) {
    f16 hq = (f16)vv[q];
    h[q] = hq;
    l[q] = (f16)(vv[q] - (float)hq);
  }
  int rt = j >> 6, rl = j & 63;
  int kt = t >> 3, gl = t & 7;
  size_t off = ((size_t)(rt * 16 + kt) << 12) + rl * 64 + ((gl ^ (rl & 7)) * 8);
  *(f16x8*)(dh + off) = h;
  *(f16x8*)(dl + off) = l;
}

// ===== K4: gemm + TRUE-last-block match, no spin (r16 verbatim; c3 zeroed by k_mask) =====
__global__ __launch_bounds__(256) void k_gemm(const f16* __restrict__ PAhi,
                                              const f16* __restrict__ PAlo,
                                              const f16* __restrict__ PBhi,
                                              const f16* __restrict__ PBlo, WS* ws) {
  __shared__ __align__(16) f16 lds[2][4][64 * 64];  // 64 KiB; aliased by match phase
  __shared__ int isLast;

  const int mid = ws->mid, n2 = ws->n2;
  const int tid = threadIdx.x;
  const int lane = tid & 63;

  {
    int L = blockIdx.x;
    int local = L >> 3;
    int bj = ((L & 7) << 1) | (local >> 4);
    int bi = local & 15;
    if (bi * 64 < mid && bj * 64 < n2) {
      const int wid = tid >> 6;
      const int wr = wid >> 1, wc = wid & 1;
      const f16* plane = (wid == 0) ? PAhi : (wid == 1) ? PAlo : (wid == 2) ? PBhi : PBlo;
      const int ptile = (wid < 2) ? bi : bj;

      f16x8 pr[8];
      auto LOAD = [&](int t) {
        const f16* tb = plane + ((size_t)((ptile << 4) + t) << 12);
        #pragma unroll
        for (int i = 0; i < 8; i++) pr[i] = *(const f16x8*)(tb + i * 512 + lane * 8);
      };
      auto STORE = [&](int buf) {
        #pragma unroll
        for (int i = 0; i < 8; i++) *(f16x8*)&lds[buf][wid][i * 512 + lane * 8] = pr[i];
      };

      const int colg = lane & 15, rowg = lane >> 4;
      const int ma0 = wr * 32 + colg, ma1 = ma0 + 16;
      const int mb0 = wc * 32 + colg, mb1 = mb0 + 16;

      f32x4 zero = {0.f, 0.f, 0.f, 0.f};
      f32x4 acc[2][2];
      acc[0][0] = zero; acc[0][1] = zero; acc[1][0] = zero; acc[1][1] = zero;

#define FRAG(buf, t4, row, g) \
  (*(const f16x8*)&lds[buf][t4][(row) * 64 + ((((g) ^ ((row) & 7))) * 8)])

      LOAD(0);
      STORE(0);
      __syncthreads();
      #pragma unroll 1
      for (int t16 = 0; t16 < 16; t16++) {
        int buf = t16 & 1;
        if (t16 < 15) LOAD(t16 + 1);
        #pragma unroll
        for (int ks = 0; ks < 2; ks++) {
          int gk = ks * 4 + rowg;
          f16x8 ah0 = FRAG(buf, 0, ma0, gk), ah1 = FRAG(buf, 0, ma1, gk);
          f16x8 al0 = FRAG(buf, 1, ma0, gk), al1 = FRAG(buf, 1, ma1, gk);
          f16x8 bh0 = FRAG(buf, 2, mb0, gk), bh1 = FRAG(buf, 2, mb1, gk);
          f16x8 bl0 = FRAG(buf, 3, mb0, gk), bl1 = FRAG(buf, 3, mb1, gk);
          acc[0][0] = __builtin_amdgcn_mfma_f32_16x16x32_f16(ah0, bh0, acc[0][0], 0, 0, 0);
          acc[0][0] = __builtin_amdgcn_mfma_f32_16x16x32_f16(ah0, bl0, acc[0][0], 0, 0, 0);
          acc[0][0] = __builtin_amdgcn_mfma_f32_16x16x32_f16(al0, bh0, acc[0][0], 0, 0, 0);
          acc[0][1] = __builtin_amdgcn_mfma_f32_16x16x32_f16(ah0, bh1, acc[0][1], 0, 0, 0);
          acc[0][1] = __builtin_amdgcn_mfma_f32_16x16x32_f16(ah0, bl1, acc[0][1], 0, 0, 0);
          acc[0][1] = __builtin_amdgcn_mfma_f32_16x16x32_f16(al0, bh1, acc[0][1], 0, 0, 0);
          acc[1][0] = __builtin_amdgcn_mfma_f32_16x16x32_f16(ah1, bh0, acc[1][0], 0, 0, 0);
          acc[1][0] = __builtin_amdgcn_mfma_f32_16x16x32_f16(ah1, bl0, acc[1][0], 0, 0, 0);
          acc[1][0] = __builtin_amdgcn_mfma_f32_16x16x32_f16(al1, bh0, acc[1][0], 0, 0, 0);
          acc[1][1] = __builtin_amdgcn_mfma_f32_16x16x32_f16(ah1, bh1, acc[1][1], 0, 0, 0);
          acc[1][1] = __builtin_amdgcn_mfma_f32_16x16x32_f16(ah1, bl1, acc[1][1], 0, 0, 0);
          acc[1][1] = __builtin_amdgcn_mfma_f32_16x16x32_f16(al1, bh1, acc[1][1], 0, 0, 0);
        }
        if (t16 < 15) {
          __syncthreads();
          STORE(buf ^ 1);
          __syncthreads();
        }
      }
#undef FRAG

      #pragma unroll
      for (int mi = 0; mi < 2; mi++) {
        #pragma unroll
        for (int i = 0; i < 4; i++) {
          int grow = bi * 64 + wr * 32 + mi * 16 + rowg * 4 + i;
          u64 key = 0;
          #pragma unroll
          for (int ni = 0; ni < 2; ni++) {
            int gcol = bj * 64 + wc * 32 + ni * 16 + colg;
            if (gcol < n2) {
              u64 k2 = packKey(acc[mi][ni][i], gcol);
              if (k2 > key) key = k2;
            }
          }
          #pragma unroll
          for (int m = 8; m; m >>= 1) {
            u64 o = (u64)__shfl_xor((long long)key, m, 64);
            if (o > key) key = o;
          }
          if (colg == 0 && grow < mid && key) atomicMax(&ws->bestKey[grow], key);
        }
      }
    }
  }
  __syncthreads();               // drains this block's atomicMaxes
  if (tid == 0) {
    unsigned c = atomicAdd(&ws->c3, 1u);
    isLast = (c == 255u);        // true chronological last (c3 zeroed by k_mask)
  }
  __syncthreads();
  if (!isLast) return;           // non-last blocks exit; NO spin

  // ---- match: decode bestKey (RMW reads) + residual compaction ----
  {
    int* flag = (int*)lds;
    int* mwsum = flag + N;
    int wv = tid >> 6;
    #pragma unroll
    for (int q = 0; q < 16; q++) flag[tid * 16 + q] = 0;
    __syncthreads();
    #pragma unroll
    for (int q = 0; q < 8; q++) {
      int r = tid + q * 256;
      if (r < mid) {
        u64 k = atomicMax(&ws->bestKey[r], 0ull);   // coherence-point read
        int j = (int)(~(unsigned)(k & 0xffffffffull));
        ws->matches[r] = j;       // crosses kernel boundary to k_write
        flag[j] = 1;              // benign race: same value
      }
    }
    __syncthreads();
    int v[8], loc[8]; int tot = 0;
    #pragma unroll
    for (int q = 0; q < 8; q++) {
      int j = tid * 8 + q;
      bool val = (j < ws->n2) && (flag[j] == 0);
      v[q] = val; loc[q] = tot; tot += (int)val;
    }
    int inc = tot;
    #pragma unroll
    for (int o = 1; o < 64; o <<= 1) { int u = __shfl_up(inc, o, 64); if (lane >= o) inc += u; }
    if (lane == 63) mwsum[wv] = inc;
    __syncthreads();
    if (tid == 0) { mwsum[1] += mwsum[0]; mwsum[2] += mwsum[1]; mwsum[3] += mwsum[2]; }
    __syncthreads();
    int base = (wv ? mwsum[wv - 1] : 0) + inc - tot;
    #pragma unroll
    for (int q = 0; q < 8; q++)
      if (v[q]) ws->residIdx[base + loc[q]] = ws->A2idx[tid * 8 + q];
    if (tid == 0) ws->n_resid = mwsum[3];
  }
}

// ===== K5: one block per output row, full occupancy (verbatim, verified) =====
__global__ __launch_bounds__(256) void k_write(const float* __restrict__ x,
                                               float* __restrict__ out, WS* ws) {
  int r = blockIdx.x;
  int t = threadIdx.x;
  int n_B = ws->n_B, mid = ws->mid, n_resid = ws->n_resid;
  float4 res = make_float4(0.f, 0.f, 0.f, 0.f);
  if (r < N) {
    if (r < n_B) {
      res = ((const float4*)(x + (size_t)ws->Bidx[r] * D))[t];
    } else if (r < n_B + mid) {
      int m = r - n_B;
      float4 v1 = ((const float4*)(x + (size_t)ws->A1idx[m] * D))[t];
      float4 v2 = ((const float4*)(x + (size_t)ws->A2idx[ws->matches[m]] * D))[t];
      res = make_float4(0.5f * (v1.x + v2.x), 0.5f * (v1.y + v2.y),
                        0.5f * (v1.z + v2.z), 0.5f * (v1.w + v2.w));
    }
  } else {
    int k = r - N;
    if (k < n_resid) {
      res = ((const float4*)(x + (size_t)ws->residIdx[k] * D))[t];
    }
  }
  ((float4*)(out + (size_t)r * D))[t] = res;
}

extern "C" void kernel_launch(void* const* d_in, const int* in_sizes, int n_in,
                              void* d_out, int out_size, void* d_ws, size_t ws_size,
                              hipStream_t stream) {
  const float* x = (const float*)d_in[0];
  const float* attn = (const float*)d_in[1];
  float* out = (float*)d_out;
  WS* ws = (WS*)d_ws;
  // d_out (33.5 MB) doubles as scratch for the tiled packed f16 planes (16 MB);
  // k_write fully overwrites it afterwards (stream-ordered, deterministic).
  f16* PAhi = (f16*)d_out;
  f16* PAlo = PAhi + PLANE;
  f16* PBhi = PAlo + PLANE;
  f16* PBlo = PBhi + PLANE;

  k_prep<<<N, 256, 0, stream>>>(x, attn, ws);
  k_mask<<<1, 1024, 0, stream>>>(ws);          // also zeroes bestKey + c3
  k_pack<<<4096, 128, 0, stream>>>(x, PAhi, PAlo, PBhi, PBlo, ws);
  k_gemm<<<256, 256, 0, stream>>>(PAhi, PAlo, PBhi, PBlo, ws);  // + last-block match
  k_write<<<2 * N, 256, 0, stream>>>(x, out, ws);
}

// Round 18
// 58.144 us; speedup vs baseline: 3.3550x; 1.0025x over previous
//
#include <hip/hip_runtime.h>

#define N 4096
#define D 1024
#define EPSF 1e-6f

typedef _Float16 f16;
typedef f16 f16x8 __attribute__((ext_vector_type(8)));
typedef float f32x4 __attribute__((ext_vector_type(4)));
typedef unsigned long long u64;

#define PLANE ((size_t)2048 * 1024)  // f16 elements per packed plane

struct WS {
  unsigned c3, pad0[3];      // zeroed by k_mask every launch (boundary-coherent)
  int n_A, mid, n2, n_B, n_resid, pad[3];
  float a[N];
  float diag[N];
  int A1idx[N];
  int A2idx[N];
  int Bidx[N];
  int matches[N];
  int residIdx[N];
  u64 bestKey[2048];
};

__device__ __forceinline__ u64 packKey(float v, int j) {
  unsigned u = __float_as_uint(v);
  unsigned m = (u & 0x80000000u) ? ~u : (u | 0x80000000u);
  return ((u64)m << 32) | (unsigned)(~(unsigned)j);
}

// ===== K1: row means of x + attn diagonal (verbatim) =====
__global__ __launch_bounds__(256) void k_prep(const float* __restrict__ x,
                                              const float* __restrict__ attn, WS* ws) {
  int row = blockIdx.x;
  int t = threadIdx.x;
  float4 v = ((const float4*)(x + (size_t)row * D))[t];
  float sm = v.x + v.y + v.z + v.w;
  for (int o = 32; o; o >>= 1) sm += __shfl_down(sm, o, 64);
  __shared__ float w[4];
  if ((t & 63) == 0) w[t >> 6] = sm;
  __syncthreads();
  if (t == 0) {
    ws->a[row] = (w[0] + w[1] + w[2] + w[3]) * (1.0f / D);
    ws->diag[row] = attn[(size_t)row * N + row];
  }
}

// ===== K2: fused mask (r17 body verbatim), launched with 64 REDUNDANT blocks.
// Every block computes identical results and writes identical values (benign
// same-value multi-writer; no global atomics) — keeps 64 CUs busy so the chip
// holds a high DPM clock state during this serial-latency-bound section. =====
__global__ __launch_bounds__(1024) void k_mask(WS* ws) {
  __shared__ double dred[16], dred2[16];
  __shared__ float bcast[2];
  __shared__ int hist[256];
  __shared__ int wsum[16];
  __shared__ unsigned sPrefix;
  __shared__ int sRank;
  int tid = threadIdx.x;
  int lane = tid & 63, wv = tid >> 6;

  ws->bestKey[tid] = 0ull;        // identical zeros from every block
  ws->bestKey[tid + 1024] = 0ull;
  if (tid == 0) ws->c3 = 0u;

  // --- stats of a ---
  float av[4];
  double s = 0.0, s2 = 0.0;
  #pragma unroll
  for (int q = 0; q < 4; q++) {
    float f = ws->a[tid * 4 + q];
    av[q] = f; s += f; s2 += (double)f * f;
  }
  for (int o = 32; o; o >>= 1) { s += __shfl_down(s, o, 64); s2 += __shfl_down(s2, o, 64); }
  if (lane == 0) { dred[wv] = s; dred2[wv] = s2; }
  __syncthreads();
  if (tid == 0) {
    double t1 = 0, t2 = 0;
    for (int i = 0; i < 16; i++) { t1 += dred[i]; t2 += dred2[i]; }
    bcast[0] = (float)(t1 / N);
    bcast[1] = (float)sqrt((t2 - t1 * t1 / N) / (N - 1));
  }
  __syncthreads();
  float meanA = bcast[0], stdA = bcast[1];

  // --- Il = z^2 * diag, plus its stats ---
  float il[4];
  s = 0.0; s2 = 0.0;
  #pragma unroll
  for (int q = 0; q < 4; q++) {
    int i = tid * 4 + q;
    float z = (av[q] - meanA) / (stdA + EPSF);
    float I = z * z * ws->diag[i];
    il[q] = I; s += I; s2 += (double)I * I;
  }
  for (int o = 32; o; o >>= 1) { s += __shfl_down(s, o, 64); s2 += __shfl_down(s2, o, 64); }
  __syncthreads();
  if (lane == 0) { dred[wv] = s; dred2[wv] = s2; }
  __syncthreads();
  if (tid == 0) {
    double t1 = 0, t2 = 0;
    for (int i = 0; i < 16; i++) { t1 += dred[i]; t2 += dred2[i]; }
    bcast[0] = (float)(t1 / N);
    bcast[1] = (float)sqrt((t2 - t1 * t1 / N) / (N - 1));
    sPrefix = 0u; sRank = (N - 1) / 2;
  }
  __syncthreads();
  float meanI = bcast[0], stdI = bcast[1];

  float sv[4]; unsigned ab[4];
  #pragma unroll
  for (int q = 0; q < 4; q++) {
    float sval = (il[q] - meanI) / (stdI + EPSF);
    sv[q] = sval;
    ab[q] = __float_as_uint(fabsf(sval));
  }

  // --- radix select rank-2047 of |s| bit patterns (parallel bucket find) ---
  for (int p = 3; p >= 0; p--) {
    if (tid < 256) hist[tid] = 0;
    __syncthreads();
    unsigned pre = sPrefix;
    int rk = sRank;
    int sh = p * 8;
    unsigned mHi = (p == 3) ? 0u : (0xFFFFFFFFu << (sh + 8));
    #pragma unroll
    for (int q = 0; q < 4; q++)
      if ((ab[q] & mHi) == pre) atomicAdd(&hist[(ab[q] >> sh) & 255], 1);
    __syncthreads();
    int v = (tid < 256) ? hist[tid] : 0;
    int inc = v;
    #pragma unroll
    for (int o = 1; o < 64; o <<= 1) { int u = __shfl_up(inc, o, 64); if (lane >= o) inc += u; }
    if (lane == 63) wsum[wv] = inc;
    __syncthreads();
    if (tid < 16) {
      int t = wsum[tid];
      #pragma unroll
      for (int o = 1; o < 16; o <<= 1) { int u = __shfl_up(t, o, 64); if (tid >= o) t += u; }
      wsum[tid] = t;
    }
    __syncthreads();
    int incl = (wv ? wsum[wv - 1] : 0) + inc;
    int E = incl - v;
    if (tid < 256 && v && rk >= E && rk < E + v) {
      sPrefix = pre | ((unsigned)tid << sh);
      sRank = rk - E;
    }
    __syncthreads();
  }
  float med = __uint_as_float(sPrefix);

  // --- mask (strict |s| > med, bit-exact) + stable compaction (wave scan) ---
  int msk[4], loc[4]; int tot = 0;
  #pragma unroll
  for (int q = 0; q < 4; q++) {
    bool m = fabsf(sv[q]) > med;
    msk[q] = m; loc[q] = tot; tot += (int)m;
  }
  int inc = tot;
  #pragma unroll
  for (int o = 1; o < 64; o <<= 1) { int u = __shfl_up(inc, o, 64); if (lane >= o) inc += u; }
  if (lane == 63) wsum[wv] = inc;
  __syncthreads();
  if (tid < 16) {
    int t = wsum[tid];
    #pragma unroll
    for (int o = 1; o < 16; o <<= 1) { int u = __shfl_up(t, o, 64); if (tid >= o) t += u; }
    wsum[tid] = t;
  }
  __syncthreads();
  int nA = wsum[15];
  int base = (wv ? wsum[wv - 1] : 0) + inc - tot;
  int midl = nA >> 1;
  #pragma unroll
  for (int q = 0; q < 4; q++) {
    int i = tid * 4 + q;
    int r = base + loc[q];
    if (msk[q]) {
      if (r < midl) ws->A1idx[r] = i; else ws->A2idx[r - midl] = i;
    } else {
      ws->Bidx[i - r] = i;
    }
  }
  if (tid == 0) { ws->n_A = nA; ws->mid = midl; ws->n2 = nA - midl; ws->n_B = N - nA; }
}

// ===== K3: gather selected rows -> tiled swizzled f16 hi/lo planes (verbatim) =====
__global__ __launch_bounds__(128) void k_pack(const float* __restrict__ x,
                                              f16* __restrict__ PAhi, f16* __restrict__ PAlo,
                                              f16* __restrict__ PBhi, f16* __restrict__ PBlo,
                                              WS* ws) {
  int b = blockIdx.x, t = threadIdx.x;
  const float* src;
  f16 *dh, *dl;
  int j;
  if (b < 2048) {
    if (b >= ws->mid) return;
    j = b;
    src = x + (size_t)ws->A1idx[b] * D;
    dh = PAhi; dl = PAlo;
  } else {
    j = b - 2048;
    if (j >= ws->n2) return;
    src = x + (size_t)ws->A2idx[j] * D;
    dh = PBhi; dl = PBlo;
  }
  float4 v0 = ((const float4*)src)[t * 2];
  float4 v1 = ((const float4*)src)[t * 2 + 1];
  float vv[8] = {v0.x, v0.y, v0.z, v0.w, v1.x, v1.y, v1.z, v1.w};
  f16x8 h, l;
  #pragma unroll
  for (int q = 0; q < 8; q++) {
    f16 hq = (f16)vv[q];
    h[q] = hq;
    l[q] = (f16)(vv[q] - (float)hq);
  }
  int rt = j >> 6, rl = j & 63;
  int kt = t >> 3, gl = t & 7;
  size_t off = ((size_t)(rt * 16 + kt) << 12) + rl * 64 + ((gl ^ (rl & 7)) * 8);
  *(f16x8*)(dh + off) = h;
  *(f16x8*)(dl + off) = l;
}

// ===== K4: gemm + TRUE-last-block match, no spin (verbatim; c3 zeroed by k_mask) =====
__global__ __launch_bounds__(256) void k_gemm(const f16* __restrict__ PAhi,
                                              const f16* __restrict__ PAlo,
                                              const f16* __restrict__ PBhi,
                                              const f16* __restrict__ PBlo, WS* ws) {
  __shared__ __align__(16) f16 lds[2][4][64 * 64];  // 64 KiB; aliased by match phase
  __shared__ int isLast;

  const int mid = ws->mid, n2 = ws->n2;
  const int tid = threadIdx.x;
  const int lane = tid & 63;

  {
    int L = blockIdx.x;
    int local = L >> 3;
    int bj = ((L & 7) << 1) | (local >> 4);
    int bi = local & 15;
    if (bi * 64 < mid && bj * 64 < n2) {
      const int wid = tid >> 6;
      const int wr = wid >> 1, wc = wid & 1;
      const f16* plane = (wid == 0) ? PAhi : (wid == 1) ? PAlo : (wid == 2) ? PBhi : PBlo;
      const int ptile = (wid < 2) ? bi : bj;

      f16x8 pr[8];
      auto LOAD = [&](int t) {
        const f16* tb = plane + ((size_t)((ptile << 4) + t) << 12);
        #pragma unroll
        for (int i = 0; i < 8; i++) pr[i] = *(const f16x8*)(tb + i * 512 + lane * 8);
      };
      auto STORE = [&](int buf) {
        #pragma unroll
        for (int i = 0; i < 8; i++) *(f16x8*)&lds[buf][wid][i * 512 + lane * 8] = pr[i];
      };

      const int colg = lane & 15, rowg = lane >> 4;
      const int ma0 = wr * 32 + colg, ma1 = ma0 + 16;
      const int mb0 = wc * 32 + colg, mb1 = mb0 + 16;

      f32x4 zero = {0.f, 0.f, 0.f, 0.f};
      f32x4 acc[2][2];
      acc[0][0] = zero; acc[0][1] = zero; acc[1][0] = zero; acc[1][1] = zero;

#define FRAG(buf, t4, row, g) \
  (*(const f16x8*)&lds[buf][t4][(row) * 64 + ((((g) ^ ((row) & 7))) * 8)])

      LOAD(0);
      STORE(0);
      __syncthreads();
      #pragma unroll 1
      for (int t16 = 0; t16 < 16; t16++) {
        int buf = t16 & 1;
        if (t16 < 15) LOAD(t16 + 1);
        #pragma unroll
        for (int ks = 0; ks < 2; ks++) {
          int gk = ks * 4 + rowg;
          f16x8 ah0 = FRAG(buf, 0, ma0, gk), ah1 = FRAG(buf, 0, ma1, gk);
          f16x8 al0 = FRAG(buf, 1, ma0, gk), al1 = FRAG(buf, 1, ma1, gk);
          f16x8 bh0 = FRAG(buf, 2, mb0, gk), bh1 = FRAG(buf, 2, mb1, gk);
          f16x8 bl0 = FRAG(buf, 3, mb0, gk), bl1 = FRAG(buf, 3, mb1, gk);
          acc[0][0] = __builtin_amdgcn_mfma_f32_16x16x32_f16(ah0, bh0, acc[0][0], 0, 0, 0);
          acc[0][0] = __builtin_amdgcn_mfma_f32_16x16x32_f16(ah0, bl0, acc[0][0], 0, 0, 0);
          acc[0][0] = __builtin_amdgcn_mfma_f32_16x16x32_f16(al0, bh0, acc[0][0], 0, 0, 0);
          acc[0][1] = __builtin_amdgcn_mfma_f32_16x16x32_f16(ah0, bh1, acc[0][1], 0, 0, 0);
          acc[0][1] = __builtin_amdgcn_mfma_f32_16x16x32_f16(ah0, bl1, acc[0][1], 0, 0, 0);
          acc[0][1] = __builtin_amdgcn_mfma_f32_16x16x32_f16(al0, bh1, acc[0][1], 0, 0, 0);
          acc[1][0] = __builtin_amdgcn_mfma_f32_16x16x32_f16(ah1, bh0, acc[1][0], 0, 0, 0);
          acc[1][0] = __builtin_amdgcn_mfma_f32_16x16x32_f16(ah1, bl0, acc[1][0], 0, 0, 0);
          acc[1][0] = __builtin_amdgcn_mfma_f32_16x16x32_f16(al1, bh0, acc[1][0], 0, 0, 0);
          acc[1][1] = __builtin_amdgcn_mfma_f32_16x16x32_f16(ah1, bh1, acc[1][1], 0, 0, 0);
          acc[1][1] = __builtin_amdgcn_mfma_f32_16x16x32_f16(ah1, bl1, acc[1][1], 0, 0, 0);
          acc[1][1] = __builtin_amdgcn_mfma_f32_16x16x32_f16(al1, bh1, acc[1][1], 0, 0, 0);
        }
        if (t16 < 15) {
          __syncthreads();
          STORE(buf ^ 1);
          __syncthreads();
        }
      }
#undef FRAG

      #pragma unroll
      for (int mi = 0; mi < 2; mi++) {
        #pragma unroll
        for (int i = 0; i < 4; i++) {
          int grow = bi * 64 + wr * 32 + mi * 16 + rowg * 4 + i;
          u64 key = 0;
          #pragma unroll
          for (int ni = 0; ni < 2; ni++) {
            int gcol = bj * 64 + wc * 32 + ni * 16 + colg;
            if (gcol < n2) {
              u64 k2 = packKey(acc[mi][ni][i], gcol);
              if (k2 > key) key = k2;
            }
          }
          #pragma unroll
          for (int m = 8; m; m >>= 1) {
            u64 o = (u64)__shfl_xor((long long)key, m, 64);
            if (o > key) key = o;
          }
          if (colg == 0 && grow < mid && key) atomicMax(&ws->bestKey[grow], key);
        }
      }
    }
  }
  __syncthreads();               // drains this block's atomicMaxes
  if (tid == 0) {
    unsigned c = atomicAdd(&ws->c3, 1u);
    isLast = (c == 255u);        // true chronological last (c3 zeroed by k_mask)
  }
  __syncthreads();
  if (!isLast) return;           // non-last blocks exit; NO spin

  // ---- match: decode bestKey (RMW reads) + residual compaction ----
  {
    int* flag = (int*)lds;
    int* mwsum = flag + N;
    int wv = tid >> 6;
    #pragma unroll
    for (int q = 0; q < 16; q++) flag[tid * 16 + q] = 0;
    __syncthreads();
    #pragma unroll
    for (int q = 0; q < 8; q++) {
      int r = tid + q * 256;
      if (r < mid) {
        u64 k = atomicMax(&ws->bestKey[r], 0ull);   // coherence-point read
        int j = (int)(~(unsigned)(k & 0xffffffffull));
        ws->matches[r] = j;       // crosses kernel boundary to k_write
        flag[j] = 1;              // benign race: same value
      }
    }
    __syncthreads();
    int v[8], loc[8]; int tot = 0;
    #pragma unroll
    for (int q = 0; q < 8; q++) {
      int j = tid * 8 + q;
      bool val = (j < ws->n2) && (flag[j] == 0);
      v[q] = val; loc[q] = tot; tot += (int)val;
    }
    int inc = tot;
    #pragma unroll
    for (int o = 1; o < 64; o <<= 1) { int u = __shfl_up(inc, o, 64); if (lane >= o) inc += u; }
    if (lane == 63) mwsum[wv] = inc;
    __syncthreads();
    if (tid == 0) { mwsum[1] += mwsum[0]; mwsum[2] += mwsum[1]; mwsum[3] += mwsum[2]; }
    __syncthreads();
    int base = (wv ? mwsum[wv - 1] : 0) + inc - tot;
    #pragma unroll
    for (int q = 0; q < 8; q++)
      if (v[q]) ws->residIdx[base + loc[q]] = ws->A2idx[tid * 8 + q];
    if (tid == 0) ws->n_resid = mwsum[3];
  }
}

// ===== K5: one block per output row, full occupancy (verbatim) =====
__global__ __launch_bounds__(256) void k_write(const float* __restrict__ x,
                                               float* __restrict__ out, WS* ws) {
  int r = blockIdx.x;
  int t = threadIdx.x;
  int n_B = ws->n_B, mid = ws->mid, n_resid = ws->n_resid;
  float4 res = make_float4(0.f, 0.f, 0.f, 0.f);
  if (r < N) {
    if (r < n_B) {
      res = ((const float4*)(x + (size_t)ws->Bidx[r] * D))[t];
    } else if (r < n_B + mid) {
      int m = r - n_B;
      float4 v1 = ((const float4*)(x + (size_t)ws->A1idx[m] * D))[t];
      float4 v2 = ((const float4*)(x + (size_t)ws->A2idx[ws->matches[m]] * D))[t];
      res = make_float4(0.5f * (v1.x + v2.x), 0.5f * (v1.y + v2.y),
                        0.5f * (v1.z + v2.z), 0.5f * (v1.w + v2.w));
    }
  } else {
    int k = r - N;
    if (k < n_resid) {
      res = ((const float4*)(x + (size_t)ws->residIdx[k] * D))[t];
    }
  }
  ((float4*)(out + (size_t)r * D))[t] = res;
}

extern "C" void kernel_launch(void* const* d_in, const int* in_sizes, int n_in,
                              void* d_out, int out_size, void* d_ws, size_t ws_size,
                              hipStream_t stream) {
  const float* x = (const float*)d_in[0];
  const float* attn = (const float*)d_in[1];
  float* out = (float*)d_out;
  WS* ws = (WS*)d_ws;
  // d_out (33.5 MB) doubles as scratch for the tiled packed f16 planes (16 MB);
  // k_write fully overwrites it afterwards (stream-ordered, deterministic).
  f16* PAhi = (f16*)d_out;
  f16* PAlo = PAhi + PLANE;
  f16* PBhi = PAlo + PLANE;
  f16* PBlo = PBhi + PLANE;

  k_prep<<<N, 256, 0, stream>>>(x, attn, ws);
  k_mask<<<64, 1024, 0, stream>>>(ws);         // 64 redundant identical blocks (clock probe)
  k_pack<<<4096, 128, 0, stream>>>(x, PAhi, PAlo, PBhi, PBlo, ws);
  k_gemm<<<256, 256, 0, stream>>>(PAhi, PAlo, PBhi, PBlo, ws);  // + last-block match
  k_write<<<2 * N, 256, 0, stream>>>(x, out, ws);
}